// Round 1
// baseline (233.739 us; speedup 1.0000x reference)
//
#include <hip/hip_runtime.h>

#define NIMG 192
#define NPIX (256*256)
#define N_TOTAL (192*65536)

__device__ __forceinline__ int refl(int i){ i = i < 0 ? -i : i; return i > 255 ? 510 - i : i; }
__device__ __forceinline__ int clmp(int i){ return i < 0 ? 0 : (i > 255 ? 255 : i); }

// ---------------- Kernel 1: blur+sobel+mag+NMS+threshold -> bitmasks ----------------
__global__ __launch_bounds__(1024) void k_edges(
    const float* __restrict__ pred, const float* __restrict__ batch,
    unsigned long long* __restrict__ masks)   // per image: [0..1023]=weak, [1024..2047]=strong
{
    const int band = blockIdx.x;          // 0..63 -> rows R..R+3
    const int iy   = blockIdx.y;          // 0..383
    const int R    = band * 4;
    const float* img = (iy < NIMG) ? (pred + (size_t)iy * NPIX)
                                   : (batch + (size_t)(iy - NIMG) * NPIX);

    __shared__ float s_img[12][256];   // global rows R-4..R+7 (reflect)
    __shared__ float s_hb [12][256];   // horizontal gaussian
    __shared__ float s_bl [8][256];    // blurred, global rows R-2..R+5
    __shared__ float s_mag[6][256];    // mag, global rows R-1..R+4 (0 outside image)

    const int tid = threadIdx.x;
    const float W0=0.0544886845f, W1=0.2442013420f, W2=0.4026199469f;

    for (int l = tid; l < 12*256; l += 1024) {
        int rr = l >> 8, cc = l & 255;
        s_img[rr][cc] = img[refl(R - 4 + rr) * 256 + cc];
    }
    __syncthreads();
    for (int l = tid; l < 12*256; l += 1024) {
        int rr = l >> 8, cc = l & 255;
        s_hb[rr][cc] = W2 * s_img[rr][cc]
                     + W1 * (s_img[rr][refl(cc-1)] + s_img[rr][refl(cc+1)])
                     + W0 * (s_img[rr][refl(cc-2)] + s_img[rr][refl(cc+2)]);
    }
    __syncthreads();
    for (int l = tid; l < 8*256; l += 1024) {
        int rr = l >> 8, cc = l & 255;  // blur row global R-2+rr uses hb rows rr..rr+4
        s_bl[rr][cc] = W2*s_hb[rr+2][cc] + W1*(s_hb[rr+1][cc]+s_hb[rr+3][cc])
                     + W0*(s_hb[rr][cc]+s_hb[rr+4][cc]);
    }
    __syncthreads();
    for (int l = tid; l < 6*256; l += 1024) {
        int mi = l >> 8, cc = l & 255;
        int m = R - 1 + mi;
        float val = 0.f;
        if (m >= 0 && m <= 255) {
            int rm = clmp(m-1)-(R-2), r0 = m-(R-2), rp = clmp(m+1)-(R-2);
            int cm = clmp(cc-1), cp = clmp(cc+1);
            float a = s_bl[rm][cm], b = s_bl[rm][cc], c2 = s_bl[rm][cp];
            float d = s_bl[r0][cm],                   e = s_bl[r0][cp];
            float f = s_bl[rp][cm], g = s_bl[rp][cc], h = s_bl[rp][cp];
            float gx = (c2 + 2.f*e + h) - (a + 2.f*d + f);
            float gy = (f + 2.f*g + h) - (a + 2.f*b + c2);
            val = sqrtf(gx*gx + gy*gy + 1e-6f);
        }
        s_mag[mi][cc] = val;
    }
    __syncthreads();
    {
        int wv = tid >> 6, lane = tid & 63;
        int row_off = wv >> 2, word = wv & 3;
        int r = R + row_off, c = word * 64 + lane;
        int rm = clmp(r-1)-(R-2), r0 = r-(R-2), rp = clmp(r+1)-(R-2);
        int cm = clmp(c-1), cp = clmp(c+1);
        float a = s_bl[rm][cm], b = s_bl[rm][c], c2 = s_bl[rm][cp];
        float d = s_bl[r0][cm],                 e = s_bl[r0][cp];
        float f = s_bl[rp][cm], g = s_bl[rp][c], h = s_bl[rp][cp];
        float gx = (c2 + 2.f*e + h) - (a + 2.f*d + f);
        float gy = (f + 2.f*g + h) - (a + 2.f*b + c2);
        float ax = fabsf(gx), ay = fabsf(gy);
        int dr, dc;
        if (ay <= 0.41421356237f * ax)      { dr = 0;  dc = 1; }   // horizontal axis
        else if (ay >= 2.41421356237f * ax) { dr = 1;  dc = 0; }   // vertical axis
        else if ((gx > 0.f) == (gy > 0.f))  { dr = -1; dc = 1; }   // 45deg axis
        else                                { dr = 1;  dc = 1; }   // 135deg axis
        float mg = s_mag[row_off+1][c];
        int n1c = c + dc, n2c = c - dc;
        float m1 = (n1c >= 0 && n1c <= 255) ? s_mag[row_off+1+dr][n1c] : 0.f;
        float m2 = (n2c >= 0 && n2c <= 255) ? s_mag[row_off+1-dr][n2c] : 0.f;
        bool keep = fminf(mg - m1, mg - m2) > 0.f;
        int e8 = keep ? ((mg > 0.1f ? 1 : 0) + (mg > 0.2f ? 1 : 0)) : 0;
        unsigned long long wm = __ballot(e8 == 1);
        unsigned long long sm = __ballot(e8 == 2);
        if (lane == 0) {
            unsigned long long* mi_ = masks + (size_t)iy * 2048;
            int rw = r * 4 + word;
            mi_[rw]        = wm;
            mi_[1024 + rw] = sm;
        }
    }
}

// ---------------- Kernel 2: hysteresis fixpoint (bitwise Jacobi) + diff count -------
__device__ __forceinline__ unsigned long long hsp(const unsigned long long* Srow, int w) {
    unsigned long long s = Srow[w];
    unsigned long long h = s | (s << 1) | (s >> 1);
    if (w > 0) h |= Srow[w-1] >> 63;
    if (w < 3) h |= Srow[w+1] << 63;
    return h;
}
__device__ __forceinline__ unsigned long long stepS(const unsigned long long* S,
        unsigned long long wword, int r, int w, int tid) {
    unsigned long long dil = hsp(S + r*4, w);
    if (r > 0)   dil |= hsp(S + (r-1)*4, w);
    if (r < 255) dil |= hsp(S + (r+1)*4, w);
    return S[tid] | (dil & wword);
}

__global__ __launch_bounds__(1024) void k_hyst(
    const unsigned long long* __restrict__ masks,
    unsigned long long* __restrict__ diff_cnt)
{
    const int b = blockIdx.x;  // image pair 0..191
    __shared__ unsigned long long Sp[1024], St[1024];
    __shared__ int flag;
    __shared__ int wsum[16];
    const int tid = threadIdx.x;
    const int r = tid >> 2, w = tid & 3;
    const unsigned long long* mp = masks + (size_t)b * 2048;
    const unsigned long long* mt = masks + (size_t)(b + NIMG) * 2048;
    unsigned long long wp = mp[tid], wt = mt[tid];
    Sp[tid] = mp[1024 + tid];
    St[tid] = mt[1024 + tid];
    if (tid == 0) flag = 0;
    __syncthreads();
    for (;;) {
        unsigned long long np_ = stepS(Sp, wp, r, w, tid);
        unsigned long long nt_ = stepS(St, wt, r, w, tid);
        bool ch = (np_ != Sp[tid]) || (nt_ != St[tid]);
        __syncthreads();                 // all reads done
        Sp[tid] = np_; St[tid] = nt_;
        if (ch) flag = 1;
        __syncthreads();                 // writes + flag visible
        if (!flag) break;                // uniform
        __syncthreads();                 // all saw flag before reset
        if (tid == 0) flag = 0;
    }
    int cnt = __popcll(Sp[tid] ^ St[tid]);
    for (int off = 32; off; off >>= 1) cnt += __shfl_down(cnt, off);
    if ((tid & 63) == 0) wsum[tid >> 6] = cnt;
    __syncthreads();
    if (tid == 0) {
        int s = 0;
        for (int i = 0; i < 16; ++i) s += wsum[i];
        atomicAdd(diff_cnt, (unsigned long long)s);
    }
}

// ---------------- Kernel 3: MSE(pred,batch) reduce ----------------------------------
__global__ __launch_bounds__(256) void k_mse(
    const float4* __restrict__ a, const float4* __restrict__ b,
    double* __restrict__ sse, int n4)
{
    int idx = blockIdx.x * blockDim.x + threadIdx.x;
    int stride = gridDim.x * blockDim.x;
    float s = 0.f;
    for (int i = idx; i < n4; i += stride) {
        float4 x = a[i], y = b[i];
        float d0 = x.x - y.x, d1 = x.y - y.y, d2 = x.z - y.z, d3 = x.w - y.w;
        s += d0*d0 + d1*d1 + d2*d2 + d3*d3;
    }
    for (int off = 32; off; off >>= 1) s += __shfl_down(s, off);
    __shared__ float wsh[4];
    if ((threadIdx.x & 63) == 0) wsh[threadIdx.x >> 6] = s;
    __syncthreads();
    if (threadIdx.x == 0)
        atomicAdd(sse, (double)(wsh[0] + wsh[1] + wsh[2] + wsh[3]));
}

// ---------------- Kernel 4: combine --------------------------------------------------
__global__ void k_final(const double* __restrict__ sse,
                        const unsigned long long* __restrict__ cnt,
                        float* __restrict__ out)
{
    double n = (double)N_TOTAL;
    float mse1 = (float)(*sse / n);
    float mse2 = (float)((double)(*cnt) / n);
    out[0] = 0.85f * mse1 + (1.0f - 0.85f) * mse2;
}

extern "C" void kernel_launch(void* const* d_in, const int* in_sizes, int n_in,
                              void* d_out, int out_size, void* d_ws, size_t ws_size,
                              hipStream_t stream)
{
    const float* pred  = (const float*)d_in[0];
    const float* batch = (const float*)d_in[1];
    float* out = (float*)d_out;
    double* sse = (double*)d_ws;
    unsigned long long* cnt = (unsigned long long*)((char*)d_ws + 8);
    unsigned long long* masks = (unsigned long long*)((char*)d_ws + 64);

    hipMemsetAsync(d_ws, 0, 64, stream);
    dim3 g1(64, 384);
    k_edges<<<g1, 1024, 0, stream>>>(pred, batch, masks);
    k_hyst<<<192, 1024, 0, stream>>>(masks, cnt);
    k_mse<<<2048, 256, 0, stream>>>((const float4*)pred, (const float4*)batch,
                                    sse, N_TOTAL / 4);
    k_final<<<1, 1, 0, stream>>>(sse, cnt, out);
}

// Round 2
// 160.339 us; speedup vs baseline: 1.4578x; 1.4578x over previous
//
#include <hip/hip_runtime.h>

#define NIMG 192
#define NPIX (256*256)
#define N_TOTAL (192*65536)

__device__ __forceinline__ int refl(int i){ i = i < 0 ? -i : i; return i > 255 ? 510 - i : i; }
__device__ __forceinline__ int clmp(int i){ return i < 0 ? 0 : (i > 255 ? 255 : i); }
__device__ __forceinline__ int mod3(int x){ return (x + 3) % 3; }

// ---------------- Kernel 1: rolling line-buffer canny front-end ----------------
// One thread per column (256 threads = 4 waves; each wave's ballot = one mask word).
// Per iteration (one bl-row b): load img row b+2 -> LDS, h-blur (LDS reads),
// v-blur in registers (5-window), sobel/mag row b-1 (3-row LDS ring),
// NMS row b-2 (3-row mag ring + own-column gx/gy kept in registers).
__global__ __launch_bounds__(256) void k_edges(
    const float* __restrict__ pred, const float* __restrict__ batch,
    unsigned long long* __restrict__ masks)   // per image: [0..1023]=weak, [1024..2047]=strong
{
    const int band = blockIdx.x;          // 0..3 -> rows band*64 .. band*64+63
    const int iy   = blockIdx.y;          // 0..383
    const int R0 = band * 64, R1 = R0 + 63;
    const float* img = (iy < NIMG) ? (pred + (size_t)iy * NPIX)
                                   : (batch + (size_t)(iy - NIMG) * NPIX);
    unsigned long long* mout = masks + (size_t)iy * 2048;

    const int c = threadIdx.x;
    const int lane = c & 63, word = c >> 6;
    // per-thread constant neighbor indices (hoisted reflect/clamp)
    const int cm1 = refl(c-1), cp1 = refl(c+1), cm2 = refl(c-2), cp2 = refl(c+2);
    const int ccm = clmp(c-1), ccp = clmp(c+1);
    const float W0f = 0.0544886850f, W1f = 0.2442013420f, W2f = 0.4026199469f;

    __shared__ float s_row[256];
    __shared__ float s_bl [3][256];
    __shared__ float s_mag[3][256];

    float hb0=0.f, hb1=0.f, hb2=0.f, hb3=0.f, hb4=0.f;  // v-blur window (rows b-2..b+2)
    float gx_p=0.f, gy_p=0.f, mg_p=0.f;                 // row b-1 values, consumed at b+1

    const int b_lo = (R0 - 2 < 0) ? 0 : R0 - 2;
    const int b_hi = R1 + 2;

    // prime h-blur window: hb rows b_lo-2 .. b_lo+1
    for (int h = b_lo - 2; h <= b_lo + 1; ++h) {
        s_row[c] = img[refl(h) * 256 + c];
        __syncthreads();
        float hb = W2f*s_row[c] + W1f*(s_row[cm1]+s_row[cp1]) + W0f*(s_row[cm2]+s_row[cp2]);
        __syncthreads();
        hb1 = hb2; hb2 = hb3; hb3 = hb4; hb4 = hb;
    }

    for (int b = b_lo; b <= b_hi; ++b) {
        // --- stage 1: img row b+2 -> LDS, h-blur, v-blur (registers) ---
        s_row[c] = img[refl(b + 2) * 256 + c];
        __syncthreads();                                  // A: s_row ready; s_mag reads done
        float hbn = W2f*s_row[c] + W1f*(s_row[cm1]+s_row[cp1]) + W0f*(s_row[cm2]+s_row[cp2]);
        hb0 = hb1; hb1 = hb2; hb2 = hb3; hb3 = hb4; hb4 = hbn;
        if (b <= 255)
            s_bl[b % 3][c] = W2f*hb2 + W1f*(hb1+hb3) + W0f*(hb0+hb4);
        __syncthreads();                                  // B: bl ring ready; s_row reads done

        // --- stage 2: sobel + magnitude for row m = b-1 ---
        const int m = b - 1;
        float gx = 0.f, gy = 0.f, mg = 0.f;
        if (m >= 0 && m <= 255) {
            const float* Bm = s_bl[clmp(m-1) % 3];
            const float* B0 = s_bl[m % 3];
            const float* Bp = s_bl[clmp(m+1) % 3];
            float a = Bm[ccm], bb = Bm[c], c2 = Bm[ccp];
            float d = B0[ccm],             e  = B0[ccp];
            float f = Bp[ccm], g  = Bp[c], h2 = Bp[ccp];
            gx = (c2 + 2.f*e + h2) - (a + 2.f*d + f);
            gy = (f + 2.f*g + h2) - (a + 2.f*bb + c2);
            mg = sqrtf(gx*gx + gy*gy + 1e-6f);
        }
        s_mag[mod3(m)][c] = mg;                           // rows outside [0,255] -> 0
        __syncthreads();                                  // C: mag ring ready; bl reads done

        // --- stage 3: NMS + threshold + ballot for row r = b-2 ---
        const int r = b - 2;
        if (r >= R0) {
            float ax = fabsf(gx_p), ay = fabsf(gy_p);
            int dr, dc;
            if (ay <= 0.41421356237f * ax)         { dr = 0;  dc = 1; }  // horizontal axis
            else if (ay >= 2.41421356237f * ax)    { dr = 1;  dc = 0; }  // vertical axis
            else if ((gx_p > 0.f) == (gy_p > 0.f)) { dr = -1; dc = 1; }  //  45deg axis
            else                                   { dr = 1;  dc = 1; }  // 135deg axis
            const float* M0 = s_mag[mod3(r)];
            const float* Ma = (dr < 0) ? s_mag[mod3(r-1)] : (dr > 0 ? s_mag[mod3(r+1)] : M0);
            const float* Mb = (dr < 0) ? s_mag[mod3(r+1)] : (dr > 0 ? s_mag[mod3(r-1)] : M0);
            int n1c = c + dc, n2c = c - dc;
            float m1 = ((unsigned)n1c <= 255u) ? Ma[n1c] : 0.f;
            float m2 = ((unsigned)n2c <= 255u) ? Mb[n2c] : 0.f;
            bool keep = (mg_p - m1 > 0.f) && (mg_p - m2 > 0.f);
            int e8 = keep ? ((mg_p > 0.1f) + (mg_p > 0.2f)) : 0;
            unsigned long long wm = __ballot(e8 == 1);
            unsigned long long sm = __ballot(e8 == 2);
            if (lane == 0) {
                int rw = r * 4 + word;
                mout[rw]        = wm;
                mout[1024 + rw] = sm;
            }
        }
        gx_p = gx; gy_p = gy; mg_p = mg;
    }
}

// ---------------- Kernel 2: hysteresis fixpoint (bitwise Jacobi) + diff count -------
__device__ __forceinline__ unsigned long long hsp(const unsigned long long* Srow, int w) {
    unsigned long long s = Srow[w];
    unsigned long long h = s | (s << 1) | (s >> 1);
    if (w > 0) h |= Srow[w-1] >> 63;
    if (w < 3) h |= Srow[w+1] << 63;
    return h;
}
__device__ __forceinline__ unsigned long long stepS(const unsigned long long* S,
        unsigned long long wword, int r, int w, int tid) {
    unsigned long long dil = hsp(S + r*4, w);
    if (r > 0)   dil |= hsp(S + (r-1)*4, w);
    if (r < 255) dil |= hsp(S + (r+1)*4, w);
    return S[tid] | (dil & wword);
}

__global__ __launch_bounds__(1024) void k_hyst(
    const unsigned long long* __restrict__ masks,
    unsigned long long* __restrict__ diff_cnt)
{
    const int b = blockIdx.x;  // image pair 0..191
    __shared__ unsigned long long Sp[1024], St[1024];
    __shared__ int flag;
    __shared__ int wsum[16];
    const int tid = threadIdx.x;
    const int r = tid >> 2, w = tid & 3;
    const unsigned long long* mp = masks + (size_t)b * 2048;
    const unsigned long long* mt = masks + (size_t)(b + NIMG) * 2048;
    unsigned long long wp = mp[tid], wt = mt[tid];
    Sp[tid] = mp[1024 + tid];
    St[tid] = mt[1024 + tid];
    if (tid == 0) flag = 0;
    __syncthreads();
    for (;;) {
        unsigned long long np_ = stepS(Sp, wp, r, w, tid);
        unsigned long long nt_ = stepS(St, wt, r, w, tid);
        bool ch = (np_ != Sp[tid]) || (nt_ != St[tid]);
        __syncthreads();                 // all reads done
        Sp[tid] = np_; St[tid] = nt_;
        if (ch) flag = 1;
        __syncthreads();                 // writes + flag visible
        if (!flag) break;                // uniform
        __syncthreads();                 // all saw flag before reset
        if (tid == 0) flag = 0;
    }
    int cnt = __popcll(Sp[tid] ^ St[tid]);
    for (int off = 32; off; off >>= 1) cnt += __shfl_down(cnt, off);
    if ((tid & 63) == 0) wsum[tid >> 6] = cnt;
    __syncthreads();
    if (tid == 0) {
        int s = 0;
        for (int i = 0; i < 16; ++i) s += wsum[i];
        atomicAdd(diff_cnt, (unsigned long long)s);
    }
}

// ---------------- Kernel 3: MSE(pred,batch) reduce ----------------------------------
__global__ __launch_bounds__(256) void k_mse(
    const float4* __restrict__ a, const float4* __restrict__ b,
    double* __restrict__ sse, int n4)
{
    int idx = blockIdx.x * blockDim.x + threadIdx.x;
    int stride = gridDim.x * blockDim.x;
    float s = 0.f;
    for (int i = idx; i < n4; i += stride) {
        float4 x = a[i], y = b[i];
        float d0 = x.x - y.x, d1 = x.y - y.y, d2 = x.z - y.z, d3 = x.w - y.w;
        s += d0*d0 + d1*d1 + d2*d2 + d3*d3;
    }
    for (int off = 32; off; off >>= 1) s += __shfl_down(s, off);
    __shared__ float wsh[4];
    if ((threadIdx.x & 63) == 0) wsh[threadIdx.x >> 6] = s;
    __syncthreads();
    if (threadIdx.x == 0)
        atomicAdd(sse, (double)(wsh[0] + wsh[1] + wsh[2] + wsh[3]));
}

// ---------------- Kernel 4: combine --------------------------------------------------
__global__ void k_final(const double* __restrict__ sse,
                        const unsigned long long* __restrict__ cnt,
                        float* __restrict__ out)
{
    double n = (double)N_TOTAL;
    float mse1 = (float)(*sse / n);
    float mse2 = (float)((double)(*cnt) / n);
    out[0] = 0.85f * mse1 + (1.0f - 0.85f) * mse2;
}

extern "C" void kernel_launch(void* const* d_in, const int* in_sizes, int n_in,
                              void* d_out, int out_size, void* d_ws, size_t ws_size,
                              hipStream_t stream)
{
    const float* pred  = (const float*)d_in[0];
    const float* batch = (const float*)d_in[1];
    float* out = (float*)d_out;
    double* sse = (double*)d_ws;
    unsigned long long* cnt = (unsigned long long*)((char*)d_ws + 8);
    unsigned long long* masks = (unsigned long long*)((char*)d_ws + 64);

    hipMemsetAsync(d_ws, 0, 64, stream);
    dim3 g1(4, 384);
    k_edges<<<g1, 256, 0, stream>>>(pred, batch, masks);
    k_hyst<<<192, 1024, 0, stream>>>(masks, cnt);
    k_mse<<<2048, 256, 0, stream>>>((const float4*)pred, (const float4*)batch,
                                    sse, N_TOTAL / 4);
    k_final<<<1, 1, 0, stream>>>(sse, cnt, out);
}

// Round 3
// 141.351 us; speedup vs baseline: 1.6536x; 1.1343x over previous
//
#include <hip/hip_runtime.h>

#define NIMG 192
#define NPIX (256*256)
#define N_TOTAL (192*65536)
#define BROWS 32

__device__ __forceinline__ int refl(int i){ i = i < 0 ? -i : i; return i > 255 ? 510 - i : i; }
__device__ __forceinline__ int clmp(int i){ return i < 0 ? 0 : (i > 255 ? 255 : i); }

// ---------------- Kernel 1: wave-independent rolling canny front-end ----------------
// One wave per (image, 32-row band). Lane handles cols c = lane + 64j, j=0..3
// (so __ballot over predicate_j IS mask word j). Wave-private LDS rings, ZERO
// __syncthreads. Per iter b: load row b+3 (prefetch), h-blur row b+2 (LDS row),
// v-blur -> bl row b (reg window, LDS ring3), sobel/mag row b-1 (LDS ring3),
// NMS row b-2 (dir from regs, neighbors from mag ring).
__global__ __launch_bounds__(256, 3) void k_edges(
    const float* __restrict__ pred, const float* __restrict__ batch,
    unsigned long long* __restrict__ masks)   // per image: [0..1023]=weak, [1024..2047]=strong
{
    const int wv = threadIdx.x >> 6, lane = threadIdx.x & 63;
    const int band = blockIdx.x * 4 + wv;            // 0..7
    const int iy   = blockIdx.y;                     // 0..383
    const int R0 = band * BROWS, R1 = R0 + BROWS - 1;
    const float* img = (iy < NIMG) ? (pred + (size_t)iy * NPIX)
                                   : (batch + (size_t)(iy - NIMG) * NPIX);
    unsigned long long* mout = masks + (size_t)iy * 2048;

    __shared__ float s_all[4][7 * 256];              // per-wave: row | bl ring3 | mag ring3
    float* srow = &s_all[wv][0];
    float* sbl  = &s_all[wv][256];
    float* smag = &s_all[wv][4 * 256];

    int cc[4], hm1[4], hp1[4], hm2[4], hp2[4], sm_[4], sp_[4];
    bool cvm[4], cvp[4];
    #pragma unroll
    for (int j = 0; j < 4; ++j) {
        int c = lane + 64 * j;
        cc[j] = c;
        hm1[j] = refl(c - 1); hp1[j] = refl(c + 1);
        hm2[j] = refl(c - 2); hp2[j] = refl(c + 2);
        sm_[j] = clmp(c - 1); sp_[j] = clmp(c + 1);
        cvm[j] = (c > 0); cvp[j] = (c < 255);
    }
    const float W0 = 0.0544886850f, W1 = 0.2442013420f, W2 = 0.4026199469f;

    float hw0[4], hw1[4], hw2[4], hw3[4], hw4[4];    // h-blur rows b-2..b+2
    float bo0[4], bo1[4], bo2[4];                    // bl own-col rows b-2,b-1,b
    float gxp[4], gyp[4], mgp[4];                    // sobel of row b-2 (prev iter)
    float rld[4], rldn[4];

    const int bstart = R0 - 6, bend = R1 + 2;
    {
        const float* rp = img + refl(bstart + 2) * 256;
        #pragma unroll
        for (int j = 0; j < 4; ++j) rld[j] = rp[cc[j]];
    }

    for (int b = bstart; b <= bend; ++b) {
        // prefetch img row b+3 for next iteration
        {
            const float* rp = img + refl(b + 3) * 256;
            #pragma unroll
            for (int j = 0; j < 4; ++j) rldn[j] = rp[cc[j]];
        }
        // ---- stage 1: row b+2 -> LDS, h-blur, push register window ----
        #pragma unroll
        for (int j = 0; j < 4; ++j) srow[cc[j]] = rld[j];
        #pragma unroll
        for (int j = 0; j < 4; ++j) {
            float h = W2 * rld[j]
                    + W1 * (srow[hm1[j]] + srow[hp1[j]])
                    + W0 * (srow[hm2[j]] + srow[hp2[j]]);
            hw0[j] = hw1[j]; hw1[j] = hw2[j]; hw2[j] = hw3[j]; hw3[j] = hw4[j]; hw4[j] = h;
        }
        // ---- stage 2: v-blur -> bl row b ----
        float bln[4];
        const bool do_bl = (b >= R0 - 2) && (b >= 0) && (b <= 255);
        if (do_bl) {
            const int sb = (b % 3) * 256;
            #pragma unroll
            for (int j = 0; j < 4; ++j) {
                bln[j] = W2*hw2[j] + W1*(hw1[j]+hw3[j]) + W0*(hw0[j]+hw4[j]);
                sbl[sb + cc[j]] = bln[j];
            }
            #pragma unroll
            for (int j = 0; j < 4; ++j) { bo0[j] = bo1[j]; bo1[j] = bo2[j]; bo2[j] = bln[j]; }
        } else {
            #pragma unroll
            for (int j = 0; j < 4; ++j) { bo0[j] = bo1[j]; bo1[j] = bo2[j]; }
        }
        // ---- stage 3: sobel + magnitude row m = b-1 ----
        const int m = b - 1;
        const bool do_mag = (m >= R0 - 1) && (m >= 0) && (m <= 255);
        float gxn[4], gyn[4], mgn[4];
        if (do_mag) {
            const int rup = m > 0 ? m - 1 : 0;
            const int rdn = m < 255 ? m + 1 : 255;
            const int su = (rup % 3) * 256, s0 = (m % 3) * 256, sd = (rdn % 3) * 256;
            const int sw = (m % 3) * 256;   // mag ring slot
            #pragma unroll
            for (int j = 0; j < 4; ++j) {
                float a  = sbl[su + sm_[j]], c2 = sbl[su + sp_[j]];
                float d  = sbl[s0 + sm_[j]], e  = sbl[s0 + sp_[j]];
                float f  = sbl[sd + sm_[j]], h2 = sbl[sd + sp_[j]];
                float b_ = (m == 0)   ? bo1[j] : bo0[j];
                float g  = (m == 255) ? bo1[j] : bo2[j];
                float gx = (c2 + 2.f*e + h2) - (a + 2.f*d + f);
                float gy = (f + 2.f*g + h2) - (a + 2.f*b_ + c2);
                float mg = sqrtf(gx*gx + gy*gy + 1e-6f);
                gxn[j] = gx; gyn[j] = gy; mgn[j] = mg;
                smag[sw + cc[j]] = mg;
            }
        }
        // ---- stage 4: NMS + threshold + ballot row r = b-2 ----
        const int r = b - 2;
        if (r >= R0 && r <= R1) {
            const int srm = (((r - 1) % 3 + 3) % 3) * 256;
            const int sr0 = (r % 3) * 256;
            const int srp = ((r + 1) % 3) * 256;
            unsigned long long wmk[4], smk[4];
            #pragma unroll
            for (int j = 0; j < 4; ++j) {
                float ax = fabsf(gxp[j]), ay = fabsf(gyp[j]);
                bool horiz = (ay <= 0.41421356237f * ax);
                bool vert  = (ay >= 2.41421356237f * ax);
                bool d45   = ((gxp[j] > 0.f) == (gyp[j] > 0.f));
                int dr = horiz ? 0 : (vert ? 1 : (d45 ? -1 : 1));
                int dc = horiz ? 1 : (vert ? 0 : 1);
                int row1 = r + dr, row2 = r - dr;
                bool rv1 = (unsigned)row1 <= 255u, rv2 = (unsigned)row2 <= 255u;
                bool cv1 = dc ? cvp[j] : true,     cv2 = dc ? cvm[j] : true;
                int sl1 = (dr == 0) ? sr0 : (dr > 0 ? srp : srm);
                int sl2 = (dr == 0) ? sr0 : (dr > 0 ? srm : srp);
                int col1 = dc ? sp_[j] : cc[j];
                int col2 = dc ? sm_[j] : cc[j];
                float m1 = (rv1 && cv1) ? smag[sl1 + col1] : 0.f;
                float m2 = (rv2 && cv2) ? smag[sl2 + col2] : 0.f;
                float mg = mgp[j];
                bool keep = (mg > m1) && (mg > m2);
                bool isw = keep && (mg > 0.1f) && !(mg > 0.2f);
                bool iss = keep && (mg > 0.2f);
                wmk[j] = __ballot(isw);
                smk[j] = __ballot(iss);
            }
            if (lane == 0) {
                #pragma unroll
                for (int j = 0; j < 4; ++j) {
                    mout[r * 4 + j]        = wmk[j];
                    mout[1024 + r * 4 + j] = smk[j];
                }
            }
        }
        if (do_mag) {
            #pragma unroll
            for (int j = 0; j < 4; ++j) { gxp[j] = gxn[j]; gyp[j] = gyn[j]; mgp[j] = mgn[j]; }
        }
        #pragma unroll
        for (int j = 0; j < 4; ++j) rld[j] = rldn[j];
    }
}

// ---------------- Kernel 2: hysteresis fixpoint (bitwise Jacobi) + diff count -------
__device__ __forceinline__ unsigned long long hsp(const unsigned long long* Srow, int w) {
    unsigned long long s = Srow[w];
    unsigned long long h = s | (s << 1) | (s >> 1);
    if (w > 0) h |= Srow[w-1] >> 63;
    if (w < 3) h |= Srow[w+1] << 63;
    return h;
}
__device__ __forceinline__ unsigned long long stepS(const unsigned long long* S,
        unsigned long long wword, int r, int w, int tid) {
    unsigned long long dil = hsp(S + r*4, w);
    if (r > 0)   dil |= hsp(S + (r-1)*4, w);
    if (r < 255) dil |= hsp(S + (r+1)*4, w);
    return S[tid] | (dil & wword);
}

__global__ __launch_bounds__(1024) void k_hyst(
    const unsigned long long* __restrict__ masks,
    unsigned long long* __restrict__ diff_cnt)
{
    const int b = blockIdx.x;  // image pair 0..191
    __shared__ unsigned long long Sp[1024], St[1024];
    __shared__ int flag;
    __shared__ int wsum[16];
    const int tid = threadIdx.x;
    const int r = tid >> 2, w = tid & 3;
    const unsigned long long* mp = masks + (size_t)b * 2048;
    const unsigned long long* mt = masks + (size_t)(b + NIMG) * 2048;
    unsigned long long wp = mp[tid], wt = mt[tid];
    Sp[tid] = mp[1024 + tid];
    St[tid] = mt[1024 + tid];
    if (tid == 0) flag = 0;
    __syncthreads();
    for (;;) {
        unsigned long long np_ = stepS(Sp, wp, r, w, tid);
        unsigned long long nt_ = stepS(St, wt, r, w, tid);
        bool ch = (np_ != Sp[tid]) || (nt_ != St[tid]);
        __syncthreads();                 // all reads done
        Sp[tid] = np_; St[tid] = nt_;
        if (ch) flag = 1;
        __syncthreads();                 // writes + flag visible
        if (!flag) break;                // uniform
        __syncthreads();                 // all saw flag before reset
        if (tid == 0) flag = 0;
    }
    int cnt = __popcll(Sp[tid] ^ St[tid]);
    for (int off = 32; off; off >>= 1) cnt += __shfl_down(cnt, off);
    if ((tid & 63) == 0) wsum[tid >> 6] = cnt;
    __syncthreads();
    if (tid == 0) {
        int s = 0;
        for (int i = 0; i < 16; ++i) s += wsum[i];
        atomicAdd(diff_cnt, (unsigned long long)s);
    }
}

// ---------------- Kernel 3: MSE(pred,batch) reduce ----------------------------------
__global__ __launch_bounds__(256) void k_mse(
    const float4* __restrict__ a, const float4* __restrict__ b,
    double* __restrict__ sse, int n4)
{
    int idx = blockIdx.x * blockDim.x + threadIdx.x;
    int stride = gridDim.x * blockDim.x;
    float s = 0.f;
    for (int i = idx; i < n4; i += stride) {
        float4 x = a[i], y = b[i];
        float d0 = x.x - y.x, d1 = x.y - y.y, d2 = x.z - y.z, d3 = x.w - y.w;
        s += d0*d0 + d1*d1 + d2*d2 + d3*d3;
    }
    for (int off = 32; off; off >>= 1) s += __shfl_down(s, off);
    __shared__ float wsh[4];
    if ((threadIdx.x & 63) == 0) wsh[threadIdx.x >> 6] = s;
    __syncthreads();
    if (threadIdx.x == 0)
        atomicAdd(sse, (double)(wsh[0] + wsh[1] + wsh[2] + wsh[3]));
}

// ---------------- Kernel 4: combine --------------------------------------------------
__global__ void k_final(const double* __restrict__ sse,
                        const unsigned long long* __restrict__ cnt,
                        float* __restrict__ out)
{
    double n = (double)N_TOTAL;
    float mse1 = (float)(*sse / n);
    float mse2 = (float)((double)(*cnt) / n);
    out[0] = 0.85f * mse1 + (1.0f - 0.85f) * mse2;
}

extern "C" void kernel_launch(void* const* d_in, const int* in_sizes, int n_in,
                              void* d_out, int out_size, void* d_ws, size_t ws_size,
                              hipStream_t stream)
{
    const float* pred  = (const float*)d_in[0];
    const float* batch = (const float*)d_in[1];
    float* out = (float*)d_out;
    double* sse = (double*)d_ws;
    unsigned long long* cnt = (unsigned long long*)((char*)d_ws + 8);
    unsigned long long* masks = (unsigned long long*)((char*)d_ws + 64);

    hipMemsetAsync(d_ws, 0, 64, stream);
    dim3 g1(2, 384);                      // blockIdx.x*4+wave = band 0..7
    k_edges<<<g1, 256, 0, stream>>>(pred, batch, masks);
    k_hyst<<<192, 1024, 0, stream>>>(masks, cnt);
    k_mse<<<2048, 256, 0, stream>>>((const float4*)pred, (const float4*)batch,
                                    sse, N_TOTAL / 4);
    k_final<<<1, 1, 0, stream>>>(sse, cnt, out);
}

// Round 4
// 80.992 us; speedup vs baseline: 2.8860x; 1.7453x over previous
//
#include <hip/hip_runtime.h>

#define NIMG 192
#define NPIX (256*256)
#define N_TOTAL (192*65536)
typedef unsigned long long u64;

__device__ __forceinline__ int refl(int i){ i = i < 0 ? -i : i; return i > 255 ? 510 - i : i; }
__device__ __forceinline__ int mod3(int x){ return ((x % 3) + 3) % 3; }

// Per-wave LDS layout (float element offsets), all data 16B-aligned where needed:
// SR: raw row; sr[k+4]=row[k]; guards sr[2]=row(refl -2)=row[2]? no: sr[2]=g(-2), sr[3]=g(-1), sr[260]=g(256), sr[261]=g(257)
// TT/UU: tt[k+1]=t[k]; guards tt[0]=t[-1], tt[257]=t[256] (clamp)
// MM: 3 ring slots of 264; mm[s][k+1]=mag2[k]; mm[s][0]=mm[s][257]=0 (init once)
#define SRo 0
#define TTo 264
#define UUo 528
#define MMo 792
#define WSTRIDE 1584

__global__ __launch_bounds__(256, 3) void k_edges(
    const float* __restrict__ pred, const float* __restrict__ batch,
    u64* __restrict__ masks, double* __restrict__ sse)
{
    const int wv = threadIdx.x >> 6, lane = threadIdx.x & 63;
    const int band = blockIdx.x * 4 + wv;            // 0..7
    const int iy   = blockIdx.y;                     // 0..383
    const int R0 = band * 32, R1 = R0 + 31;
    const bool isPred = iy < NIMG;
    const float* img  = isPred ? pred  + (size_t)iy * NPIX : batch + (size_t)(iy - NIMG) * NPIX;
    const float* oimg = isPred ? batch + (size_t)iy * NPIX : pred  + (size_t)(iy - NIMG) * NPIX;
    u64* mout = masks + (size_t)iy * 2048;
    const int mlo = isPred ? R0 : R0 + 16;           // MSE row range for this wave
    const int mhi = isPred ? R0 + 15 : R1;

    __shared__ float lds[4][WSTRIDE];
    float* W = lds[wv];

    // zero the mag guards once (never touched again)
    if (lane < 2) {
        int gi = (lane == 0) ? 0 : 257;
        W[MMo + gi] = 0.f; W[MMo + 264 + gi] = 0.f; W[MMo + 528 + gi] = 0.f;
    }

    const float W0 = 0.0544886850f, W1 = 0.2442013420f, W2 = 0.4026199469f;
    const float LO2 = 0.1f * 0.1f, HI2 = 0.2f * 0.2f;

    float hw0[4], hw1[4], hw2[4], hw3[4], hw4[4];    // h-blur rows b-2..b+2
    float bo0[4], bo1[4], bo2[4];                    // own-col blurred rows b-2,b-1,b
    float gxp[4], gyp[4], mgp[4];                    // sobel/mag2 of row b-2
    float4 cur, ocur = make_float4(0.f,0.f,0.f,0.f);
    float acc = 0.f;
    const float4* ldp = nullptr;

    const int bstart = R0 - 6, bend = R1 + 2;
    cur = *(const float4*)(img + (size_t)refl(bstart + 2) * 256 + (lane << 2));

    auto step = [&](int b_, int mmW_, int mmR_, int mmM_, bool fast, bool nmsOn) {
        // 1: prefetch raw row b+3
        float4 nxt;
        if (fast) { nxt = *ldp; ldp += 64; }
        else      { nxt = *(const float4*)(img + (size_t)refl(b_ + 3) * 256 + (lane << 2)); }
        // 1b: prefetch counterpart row b+3 (for MSE next iter)
        float4 onxt = ocur;
        if (b_ + 3 >= mlo && b_ + 3 <= mhi)
            onxt = *(const float4*)(oimg + (size_t)(b_ + 3) * 256 + (lane << 2));
        // 2: MSE consume row b+2
        if (b_ + 2 >= mlo && b_ + 2 <= mhi) {
            float dx = cur.x - ocur.x, dy = cur.y - ocur.y;
            float dz = cur.z - ocur.z, dw = cur.w - ocur.w;
            acc += dx*dx + dy*dy + dz*dz + dw*dw;
        }
        // 3: raw row -> LDS (+ reflect guards)
        *reinterpret_cast<float4*>(&W[SRo + 4 + (lane << 2)]) = cur;
        if (lane == 0 || lane == 63) {
            int ga = (lane == 0) ? (SRo + 2) : (SRo + 260);
            W[ga] = cur.z; W[ga + 1] = cur.y;    // g(-2)=row[2],g(-1)=row[1] / g(256)=row[254],g(257)=row[253]
        }
        // 4: h-blur row b+2 (LDS), push hw window, v-blur row b, t/u row m=b-1
        float tJ[4], uJ[4];
        #pragma unroll
        for (int j = 0; j < 4; ++j) {
            int ci = SRo + 4 + lane + 64*j;
            float hbn = W2*W[ci] + W1*(W[ci-1] + W[ci+1]) + W0*(W[ci-2] + W[ci+2]);
            hw0[j]=hw1[j]; hw1[j]=hw2[j]; hw2[j]=hw3[j]; hw3[j]=hw4[j]; hw4[j]=hbn;
            float bl = W2*hw2[j] + W1*(hw1[j] + hw3[j]) + W0*(hw0[j] + hw4[j]);
            bo0[j]=bo1[j]; bo1[j]=bo2[j]; bo2[j]=bl;
            float lo, hi;
            if (fast) { lo = bo0[j]; hi = bo2[j]; }
            else {
                int m_ = b_ - 1;
                lo = (m_ == 0)   ? bo1[j] : bo0[j];
                hi = (m_ == 255) ? bo1[j] : bo2[j];
            }
            tJ[j] = lo + 2.f*bo1[j] + hi;
            uJ[j] = hi - lo;
            W[TTo + 1 + lane + 64*j] = tJ[j];
            W[UUo + 1 + lane + 64*j] = uJ[j];
        }
        if (lane == 0 || lane == 63) {           // clamp guards for t,u
            int ga = (lane == 0) ? 0 : 257;
            W[TTo + ga] = (lane == 0) ? tJ[0] : tJ[3];
            W[UUo + ga] = (lane == 0) ? uJ[0] : uJ[3];
        }
        // 5: gx,gy,mag2 row m=b-1 -> ring
        float gxn[4], gyn[4], mgn[4];
        #pragma unroll
        for (int j = 0; j < 4; ++j) {
            int ti = TTo + 1 + lane + 64*j, ui = UUo + 1 + lane + 64*j;
            float gx = W[ti+1] - W[ti-1];
            float gy = W[ui-1] + 2.f*uJ[j] + W[ui+1];
            float m2v = fmaf(gx, gx, fmaf(gy, gy, 1e-6f));
            if (!fast) {
                int m_ = b_ - 1;
                bool mv = (m_ >= 0) && (m_ <= 255);
                gx = mv ? gx : 0.f; gy = mv ? gy : 0.f; m2v = mv ? m2v : 0.f;
            }
            gxn[j]=gx; gyn[j]=gy; mgn[j]=m2v;
            W[mmW_ + 1 + lane + 64*j] = m2v;
        }
        // 6: NMS + threshold + ballot for row r=b-2
        if (nmsOn) {
            const int r_ = b_ - 2;
            if (fast || r_ >= R0) {
                u64 bwv[4], bsv[4];
                #pragma unroll
                for (int j = 0; j < 4; ++j) {
                    float gx = gxp[j], gy = gyp[j], mg = mgp[j];
                    float ax = fabsf(gx), ay = fabsf(gy);
                    bool horiz = ay <= 0.41421356237f * ax;
                    bool vert  = ay >= 2.41421356237f * ax;
                    bool diag  = !horiz && !vert;
                    bool d45   = ((__float_as_uint(gx) ^ __float_as_uint(gy)) >> 31) == 0u;
                    int sA = horiz ? mmR_ : ((diag && d45) ? mmM_ : mmW_);
                    int sB = horiz ? mmR_ : ((diag && d45) ? mmW_ : mmM_);
                    int off = vert ? 0 : 1;
                    int ib = 1 + lane + 64*j;
                    float m1 = W[sA + ib + off];
                    float m2 = W[sB + ib - off];
                    bool keep = (mg > m1) && (mg > m2);
                    bwv[j] = __ballot(keep && (mg > LO2) && !(mg > HI2));
                    bsv[j] = __ballot(keep && (mg > HI2));
                }
                if (lane == 0) {
                    ulonglong2 v;
                    ulonglong2* p = (ulonglong2*)(mout + r_*4);
                    v.x = bwv[0]; v.y = bwv[1]; p[0] = v;
                    v.x = bwv[2]; v.y = bwv[3]; p[1] = v;
                    ulonglong2* q = (ulonglong2*)(mout + 1024 + r_*4);
                    v.x = bsv[0]; v.y = bsv[1]; q[0] = v;
                    v.x = bsv[2]; v.y = bsv[3]; q[1] = v;
                }
            }
        }
        // 7: rotate
        #pragma unroll
        for (int j = 0; j < 4; ++j) { gxp[j]=gxn[j]; gyp[j]=gyn[j]; mgp[j]=mgn[j]; }
        cur = nxt; ocur = onxt;
    };

    // --- phase A: prime (slow, no NMS) ---
    int b = bstart;
    for (; b < R0 + 2; ++b)
        step(b, MMo + mod3(b+2)*264, MMo + mod3(b+1)*264, MMo + mod3(b)*264, false, false);
    // --- phase B: branch-free interior, unrolled by 3 (compile-time ring slots) ---
    const int blast = (R1 + 2 < 252) ? (R1 + 2) : 252;
    ldp = (const float4*)(img + (size_t)(b + 3) * 256) + lane;
    {
        const int p = b % 3;   // b = R0+2 here; SB=b%3 -> slots sW=(SB+2)%3, sR=(SB+1)%3, sM=SB
        #define FB(BB, SW, SRR, SM) step((BB), MMo+(SW)*264, MMo+(SRR)*264, MMo+(SM)*264, true, true)
        if (p == 0)      { for (; b + 2 <= blast; b += 3) { FB(b,2,1,0); FB(b+1,0,2,1); FB(b+2,1,0,2); } }
        else if (p == 1) { for (; b + 2 <= blast; b += 3) { FB(b,0,2,1); FB(b+1,1,0,2); FB(b+2,2,1,0); } }
        else             { for (; b + 2 <= blast; b += 3) { FB(b,1,0,2); FB(b+1,2,1,0); FB(b+2,0,2,1); } }
        #undef FB
    }
    // --- phase C: remainder + bottom boundary (slow, NMS on) ---
    for (; b <= bend; ++b)
        step(b, MMo + mod3(b+2)*264, MMo + mod3(b+1)*264, MMo + mod3(b)*264, false, true);

    // MSE wave reduction -> slotted double atomics
    for (int off = 32; off; off >>= 1) acc += __shfl_down(acc, off);
    if (lane == 0)
        atomicAdd(&sse[(blockIdx.y * 2 + blockIdx.x) & 63], (double)acc);
}

// ---------------- Kernel 2: per-image hysteresis fixpoint (rows in registers) -------
__global__ __launch_bounds__(256) void k_hyst(u64* __restrict__ masks)
{
    const int im = blockIdx.x;                       // image 0..383
    u64* m = masks + (size_t)im * 2048;
    const int r = threadIdx.x;                       // row 0..255
    __shared__ u64 hd[4][256];
    __shared__ int flg[2];
    ulonglong2 wa = *(const ulonglong2*)(m + r*4);
    ulonglong2 wb = *(const ulonglong2*)(m + r*4 + 2);
    ulonglong2 sa = *(const ulonglong2*)(m + 1024 + r*4);
    ulonglong2 sb = *(const ulonglong2*)(m + 1024 + r*4 + 2);
    u64 ww0=wa.x, ww1=wa.y, ww2=wb.x, ww3=wb.y;
    u64 s0=sa.x, s1=sa.y, s2=sb.x, s3=sb.y;
    if (r < 2) flg[r] = 0;
    const int up = (r > 0) ? r - 1 : 0, dn = (r < 255) ? r + 1 : 255;  // clamped: own-row re-OR is harmless
    for (int k = 0;; ++k) {
        u64 h0 = s0 | (s0<<1) | (s0>>1) | (s1<<63);
        u64 h1 = s1 | (s1<<1) | (s1>>1) | (s0>>63) | (s2<<63);
        u64 h2 = s2 | (s2<<1) | (s2>>1) | (s1>>63) | (s3<<63);
        u64 h3 = s3 | (s3<<1) | (s3>>1) | (s2>>63);
        hd[0][r]=h0; hd[1][r]=h1; hd[2][r]=h2; hd[3][r]=h3;
        if (r == 0) flg[(k+1)&1] = 0;
        __syncthreads();
        u64 n0 = s0 | ((h0 | hd[0][up] | hd[0][dn]) & ww0);
        u64 n1 = s1 | ((h1 | hd[1][up] | hd[1][dn]) & ww1);
        u64 n2 = s2 | ((h2 | hd[2][up] | hd[2][dn]) & ww2);
        u64 n3 = s3 | ((h3 | hd[3][up] | hd[3][dn]) & ww3);
        bool ch = ((n0^s0) | (n1^s1) | (n2^s2) | (n3^s3)) != 0ULL;
        s0=n0; s1=n1; s2=n2; s3=n3;
        if (ch) flg[k&1] = 1;
        __syncthreads();
        if (!flg[k&1]) break;
    }
    ulonglong2 o;
    o.x = s0; o.y = s1; *(ulonglong2*)(m + 1024 + r*4)     = o;
    o.x = s2; o.y = s3; *(ulonglong2*)(m + 1024 + r*4 + 2) = o;
}

// ---------------- Kernel 3: XOR-popcount of final strong masks ----------------------
__global__ __launch_bounds__(256) void k_diff(const u64* __restrict__ masks, u64* __restrict__ cnt)
{
    const int b = blockIdx.x;                        // pair 0..191
    const u64* sp = masks + (size_t)b * 2048 + 1024;
    const u64* st = masks + (size_t)(b + NIMG) * 2048 + 1024;
    int c = 0;
    for (int k = threadIdx.x; k < 1024; k += 256)
        c += __popcll(sp[k] ^ st[k]);
    for (int off = 32; off; off >>= 1) c += __shfl_down(c, off);
    __shared__ int wsum[4];
    if ((threadIdx.x & 63) == 0) wsum[threadIdx.x >> 6] = c;
    __syncthreads();
    if (threadIdx.x == 0)
        atomicAdd(cnt, (u64)(wsum[0] + wsum[1] + wsum[2] + wsum[3]));
}

// ---------------- Kernel 4: combine --------------------------------------------------
__global__ void k_final(const double* __restrict__ sse, const u64* __restrict__ cnt,
                        float* __restrict__ out)
{
    double s = 0.0;
    for (int i = 0; i < 64; ++i) s += sse[i];
    float mse1 = (float)(s / (double)N_TOTAL);
    float mse2 = (float)((double)(*cnt) / (double)N_TOTAL);
    out[0] = 0.85f * mse1 + (1.0f - 0.85f) * mse2;
}

extern "C" void kernel_launch(void* const* d_in, const int* in_sizes, int n_in,
                              void* d_out, int out_size, void* d_ws, size_t ws_size,
                              hipStream_t stream)
{
    const float* pred  = (const float*)d_in[0];
    const float* batch = (const float*)d_in[1];
    float* out = (float*)d_out;
    double* sse = (double*)d_ws;                       // 64 doubles
    u64* cnt    = (u64*)((char*)d_ws + 512);
    u64* masks  = (u64*)((char*)d_ws + 1024);          // 384 * 2048 u64

    hipMemsetAsync(d_ws, 0, 1024, stream);
    dim3 g1(2, 384);
    k_edges<<<g1, 256, 0, stream>>>(pred, batch, masks, sse);
    k_hyst<<<384, 256, 0, stream>>>(masks);
    k_diff<<<192, 256, 0, stream>>>(masks, cnt);
    k_final<<<1, 1, 0, stream>>>(sse, cnt, out);
}

// Round 5
// 77.080 us; speedup vs baseline: 3.0324x; 1.0507x over previous
//
#include <hip/hip_runtime.h>

#define NIMG 192
#define NPIX (256*256)
#define N_TOTAL (192*65536)
typedef unsigned long long u64;

__device__ __forceinline__ int refl(int i){ i = i < 0 ? -i : i; return i > 255 ? 510 - i : i; }

// ---------------- Kernel 1: all-register rolling canny front-end ----------------
// One wave per (image, 32-row band). Lane owns 4 CONTIGUOUS cols [4l,4l+3].
// Mask-bit convention (consumed by k_hyst/k_diff below): word j of a row holds
// cols {4l+j}, bit l = col 4l+j.  All horizontal neighbor access via
// __shfl_up/down(1) + seam patches; zero LDS, zero barriers.
__global__ __launch_bounds__(256, 3) void k_edges(
    const float* __restrict__ pred, const float* __restrict__ batch,
    u64* __restrict__ masks, double* __restrict__ sse)
{
    const int wv = threadIdx.x >> 6, lane = threadIdx.x & 63;
    const int band = blockIdx.x * 4 + wv;            // 0..7
    const int iy   = blockIdx.y;                     // 0..383
    const int R0 = band * 32, R1 = R0 + 31;
    const bool isPred = iy < NIMG;
    const float* img  = isPred ? pred  + (size_t)iy * NPIX : batch + (size_t)(iy - NIMG) * NPIX;
    const float* oimg = isPred ? batch + (size_t)iy * NPIX : pred  + (size_t)(iy - NIMG) * NPIX;
    u64* mout = masks + (size_t)iy * 2048;
    const int mlo = isPred ? R0 : R0 + 16;           // MSE row split between the two waves
    const int mhi = isPred ? R0 + 15 : R1;

    const bool l0 = (lane == 0), l63 = (lane == 63);
    const float W0 = 0.0544886850f, W1 = 0.2442013420f, W2 = 0.4026199469f;
    const float LO2 = 0.1f * 0.1f, HI2 = 0.2f * 0.2f;
    const float T1 = 0.41421356237f, T2 = 2.41421356237f;

    float hw0[4], hw1[4], hw2[4], hw3[4], hw4[4];    // h-blur rows b-2..b+2
    float bo0[4], bo1[4], bo2[4];                    // v-blur rows b-2,b-1,b
    float mgA[4], mgB[4], mgC[4];                    // mag2 ring rows r-1,r,r+1 (after rotate)
    float mgAL, mgAR, mgBL, mgBR, mgCL, mgCR;        // their cross-lane L/R neighbors
    float gxp[4], gyp[4];                            // sobel of row r (prev iter)
    float4 cur;
    float acc = 0.f;

    #pragma unroll
    for (int k = 0; k < 4; ++k) {
        hw0[k]=hw1[k]=hw2[k]=hw3[k]=hw4[k]=0.f; bo0[k]=bo1[k]=bo2[k]=0.f;
        mgA[k]=mgB[k]=mgC[k]=0.f; gxp[k]=gyp[k]=0.f;
    }
    mgAL=mgAR=mgBL=mgBR=mgCL=mgCR=0.f;

    const int bstart = R0 - 6;
    cur = *(const float4*)(img + refl(bstart + 2) * 256 + (lane << 2));

    auto step = [&](const int b, const bool FAST) {
        // ---- loads (prefetch next raw row; counterpart row for MSE) ----
        float4 nxt = FAST ? *(const float4*)(img + ((b + 3) << 8) + (lane << 2))
                          : *(const float4*)(img + refl(b + 3) * 256 + (lane << 2));
        const bool doMSE = (b + 2 >= mlo) && (b + 2 <= mhi);
        float4 oc;
        if (doMSE) oc = *(const float4*)(oimg + ((b + 2) << 8) + (lane << 2));

        // ---- h-blur row b+2 (cross-lane via shfl, reflect seams) ----
        float Lz = __shfl_up(cur.z, 1), Lw = __shfl_up(cur.w, 1);
        float Rx = __shfl_down(cur.x, 1), Ry = __shfl_down(cur.y, 1);
        Lz = l0 ? cur.z : Lz;  Lw = l0 ? cur.y : Lw;     // cols -2,-1 -> refl 2,1
        Rx = l63 ? cur.z : Rx; Ry = l63 ? cur.y : Ry;    // cols 256,257 -> refl 254,253
        float hb[4];
        hb[0] = W0*(Lz + cur.z)   + W1*(Lw + cur.y)    + W2*cur.x;
        hb[1] = W0*(Lw + cur.w)   + W1*(cur.x + cur.z) + W2*cur.y;
        hb[2] = W0*(cur.x + Rx)   + W1*(cur.y + cur.w) + W2*cur.z;
        hb[3] = W0*(cur.y + Ry)   + W1*(cur.z + Rx)    + W2*cur.w;

        // ---- v-blur row b (register window) ----
        #pragma unroll
        for (int k = 0; k < 4; ++k) {
            hw0[k]=hw1[k]; hw1[k]=hw2[k]; hw2[k]=hw3[k]; hw3[k]=hw4[k]; hw4[k]=hb[k];
            float bl = W0*(hw0[k]+hw4[k]) + W1*(hw1[k]+hw3[k]) + W2*hw2[k];
            bo0[k]=bo1[k]; bo1[k]=bo2[k]; bo2[k]=bl;
        }

        // ---- t,u row m=b-1 (vertical sobel components), then gx,gy,mag2 ----
        const int m = b - 1;
        float t[4], u[4];
        #pragma unroll
        for (int k = 0; k < 4; ++k) {
            float lo = bo0[k], hi = bo2[k];
            if (!FAST) { if (m == 0) lo = bo1[k]; if (m == 255) hi = bo1[k]; }
            t[k] = lo + 2.f*bo1[k] + hi;
            u[k] = hi - lo;
        }
        float Lt = __shfl_up(t[3], 1), Rt = __shfl_down(t[0], 1);
        float Lu = __shfl_up(u[3], 1), Ru = __shfl_down(u[0], 1);
        Lt = l0 ? t[0] : Lt;  Rt = l63 ? t[3] : Rt;      // edge-pad clamp
        Lu = l0 ? u[0] : Lu;  Ru = l63 ? u[3] : Ru;
        float gx[4], gy[4], mg[4];
        gx[0] = t[1] - Lt;  gx[1] = t[2] - t[0];  gx[2] = t[3] - t[1];  gx[3] = Rt - t[2];
        gy[0] = Lu  + 2.f*u[0] + u[1];
        gy[1] = u[0] + 2.f*u[1] + u[2];
        gy[2] = u[1] + 2.f*u[2] + u[3];
        gy[3] = u[2] + 2.f*u[3] + Ru;
        #pragma unroll
        for (int k = 0; k < 4; ++k) mg[k] = fmaf(gx[k], gx[k], fmaf(gy[k], gy[k], 1e-6f));
        float Lm = __shfl_up(mg[3], 1), Rm = __shfl_down(mg[0], 1);
        Lm = l0 ? 0.f : Lm;  Rm = l63 ? 0.f : Rm;        // zero-pad for NMS cols
        if (!FAST && (m < 0 || m > 255)) {               // zero-pad rows for NMS
            #pragma unroll
            for (int k = 0; k < 4; ++k) mg[k] = 0.f;
            Lm = 0.f; Rm = 0.f;
        }

        // ---- rotate mag ring: now A=row b-3, B=row b-2, C=row b-1 ----
        #pragma unroll
        for (int k = 0; k < 4; ++k) { mgA[k]=mgB[k]; mgB[k]=mgC[k]; mgC[k]=mg[k]; }
        mgAL=mgBL; mgBL=mgCL; mgCL=Lm;  mgAR=mgBR; mgBR=mgCR; mgCR=Rm;

        // ---- NMS + threshold row r = b-2 (dir from gxp/gyp of row r) ----
        const int r = b - 2;
        if (FAST || (r >= R0 && r <= R1)) {
            bool wk[4], st[4];
            #pragma unroll
            for (int k = 0; k < 4; ++k) {
                float gxv = gxp[k], gyv = gyp[k];
                float ax = fabsf(gxv), ay = fabsf(gyv);
                bool horiz = (ay <= T1 * ax);
                bool vert  = (ay >= T2 * ax);
                bool d45   = ((__float_as_uint(gxv) ^ __float_as_uint(gyv)) >> 31) == 0u;
                float Bp  = (k < 3) ? mgB[k+1] : mgBR;
                float Bmv = (k > 0) ? mgB[k-1] : mgBL;
                float Ap  = (k < 3) ? mgA[k+1] : mgAR;
                float Amv = (k > 0) ? mgA[k-1] : mgAL;
                float Cp  = (k < 3) ? mgC[k+1] : mgCR;
                float Cmv = (k > 0) ? mgC[k-1] : mgCL;
                float m1 = d45 ? Ap  : Cp;   m1 = vert ? mgC[k] : m1;  m1 = horiz ? Bp  : m1;
                float m2 = d45 ? Cmv : Amv;  m2 = vert ? mgA[k] : m2;  m2 = horiz ? Bmv : m2;
                float v = mgB[k];
                bool keep = (v > m1) && (v > m2);
                wk[k] = keep && (v > LO2) && !(v > HI2);
                st[k] = keep && (v > HI2);
            }
            u64 bw0 = __ballot(wk[0]), bw1 = __ballot(wk[1]), bw2 = __ballot(wk[2]), bw3 = __ballot(wk[3]);
            u64 bs0 = __ballot(st[0]), bs1 = __ballot(st[1]), bs2 = __ballot(st[2]), bs3 = __ballot(st[3]);
            if (l0) {
                ulonglong2 v2;
                ulonglong2* p = (ulonglong2*)(mout + r * 4);
                v2.x = bw0; v2.y = bw1; p[0] = v2;
                v2.x = bw2; v2.y = bw3; p[1] = v2;
                ulonglong2* q = (ulonglong2*)(mout + 1024 + r * 4);
                v2.x = bs0; v2.y = bs1; q[0] = v2;
                v2.x = bs2; v2.y = bs3; q[1] = v2;
            }
        }

        // ---- MSE row b+2 (late consume) + rotate sobel regs ----
        if (doMSE) {
            float dx = cur.x - oc.x, dy = cur.y - oc.y, dz = cur.z - oc.z, dw = cur.w - oc.w;
            acc += dx*dx + dy*dy + dz*dz + dw*dw;
        }
        #pragma unroll
        for (int k = 0; k < 4; ++k) { gxp[k] = gx[k]; gyp[k] = gy[k]; }
        cur = nxt;
    };

    int b = bstart;
    for (; b <= R0 + 1; ++b) step(b, false);             // prime (8 iters)
    const int bfe = (R1 + 2 < 252) ? (R1 + 2) : 252;
    #pragma unroll 4
    for (; b <= bfe; ++b) step(b, true);                 // branch-free interior
    for (; b <= R1 + 2; ++b) step(b, false);             // bottom boundary (band 7)

    for (int off = 32; off; off >>= 1) acc += __shfl_down(acc, off);
    if (lane == 0)
        atomicAdd(&sse[(blockIdx.y * 2 + blockIdx.x) & 63], (double)acc);
}

// ---------------- Kernel 2: per-image hysteresis fixpoint (rows in registers) -------
// NOTE bit convention: word j bit l = col 4l+j (matches k_edges ballots).
__global__ __launch_bounds__(256) void k_hyst(u64* __restrict__ masks)
{
    const int im = blockIdx.x;                       // image 0..383
    u64* m = masks + (size_t)im * 2048;
    const int r = threadIdx.x;                       // row 0..255
    __shared__ u64 hd[4][256];
    __shared__ int flg[2];
    ulonglong2 wa = *(const ulonglong2*)(m + r*4);
    ulonglong2 wb = *(const ulonglong2*)(m + r*4 + 2);
    ulonglong2 sa = *(const ulonglong2*)(m + 1024 + r*4);
    ulonglong2 sb = *(const ulonglong2*)(m + 1024 + r*4 + 2);
    u64 ww0=wa.x, ww1=wa.y, ww2=wb.x, ww3=wb.y;
    u64 s0=sa.x, s1=sa.y, s2=sb.x, s3=sb.y;
    if (r < 2) flg[r] = 0;
    const int up = (r > 0) ? r - 1 : 0, dn = (r < 255) ? r + 1 : 255;
    for (int k = 0;; ++k) {
        u64 h0 = s0 | (s3 << 1) | s1;               // col-1 of word0 lives in word3<<1
        u64 h1 = s1 | s0 | s2;
        u64 h2 = s2 | s1 | s3;
        u64 h3 = s3 | s2 | (s0 >> 1);
        hd[0][r]=h0; hd[1][r]=h1; hd[2][r]=h2; hd[3][r]=h3;
        if (r == 0) flg[(k+1)&1] = 0;
        __syncthreads();
        u64 n0 = s0 | ((h0 | hd[0][up] | hd[0][dn]) & ww0);
        u64 n1 = s1 | ((h1 | hd[1][up] | hd[1][dn]) & ww1);
        u64 n2 = s2 | ((h2 | hd[2][up] | hd[2][dn]) & ww2);
        u64 n3 = s3 | ((h3 | hd[3][up] | hd[3][dn]) & ww3);
        bool ch = ((n0^s0) | (n1^s1) | (n2^s2) | (n3^s3)) != 0ULL;
        s0=n0; s1=n1; s2=n2; s3=n3;
        if (ch) flg[k&1] = 1;
        __syncthreads();
        if (!flg[k&1]) break;
    }
    ulonglong2 o;
    o.x = s0; o.y = s1; *(ulonglong2*)(m + 1024 + r*4)     = o;
    o.x = s2; o.y = s3; *(ulonglong2*)(m + 1024 + r*4 + 2) = o;
}

// ---------------- Kernel 3: XOR-popcount of final strong masks ----------------------
__global__ __launch_bounds__(256) void k_diff(const u64* __restrict__ masks, u64* __restrict__ cnt)
{
    const int b = blockIdx.x;                        // pair 0..191
    const u64* sp = masks + (size_t)b * 2048 + 1024;
    const u64* st = masks + (size_t)(b + NIMG) * 2048 + 1024;
    int c = 0;
    for (int k = threadIdx.x; k < 1024; k += 256)
        c += __popcll(sp[k] ^ st[k]);
    for (int off = 32; off; off >>= 1) c += __shfl_down(c, off);
    __shared__ int wsum[4];
    if ((threadIdx.x & 63) == 0) wsum[threadIdx.x >> 6] = c;
    __syncthreads();
    if (threadIdx.x == 0)
        atomicAdd(cnt, (u64)(wsum[0] + wsum[1] + wsum[2] + wsum[3]));
}

// ---------------- Kernel 4: combine --------------------------------------------------
__global__ void k_final(const double* __restrict__ sse, const u64* __restrict__ cnt,
                        float* __restrict__ out)
{
    double s = 0.0;
    for (int i = 0; i < 64; ++i) s += sse[i];
    float mse1 = (float)(s / (double)N_TOTAL);
    float mse2 = (float)((double)(*cnt) / (double)N_TOTAL);
    out[0] = 0.85f * mse1 + (1.0f - 0.85f) * mse2;
}

extern "C" void kernel_launch(void* const* d_in, const int* in_sizes, int n_in,
                              void* d_out, int out_size, void* d_ws, size_t ws_size,
                              hipStream_t stream)
{
    const float* pred  = (const float*)d_in[0];
    const float* batch = (const float*)d_in[1];
    float* out = (float*)d_out;
    double* sse = (double*)d_ws;                       // 64 doubles
    u64* cnt    = (u64*)((char*)d_ws + 512);
    u64* masks  = (u64*)((char*)d_ws + 1024);          // 384 * 2048 u64

    hipMemsetAsync(d_ws, 0, 1024, stream);
    dim3 g1(2, 384);
    k_edges<<<g1, 256, 0, stream>>>(pred, batch, masks, sse);
    k_hyst<<<384, 256, 0, stream>>>(masks);
    k_diff<<<192, 256, 0, stream>>>(masks, cnt);
    k_final<<<1, 1, 0, stream>>>(sse, cnt, out);
}

// Round 6
// 76.340 us; speedup vs baseline: 3.0618x; 1.0097x over previous
//
#include <hip/hip_runtime.h>

#define NIMG 192
#define NPIX (256*256)
#define N_TOTAL (192*65536)
typedef unsigned long long u64;

__device__ __forceinline__ int refl(int i){ i = i < 0 ? -i : i; return i > 255 ? 510 - i : i; }

// DPP wave-wide lane shifts (gfx9/CDNA). shr1: lane n <- lane n-1 (lane0 -> oldv).
// shl1: lane n <- lane n+1 (lane63 -> oldv). *z variants: invalid lane -> 0.
__device__ __forceinline__ float dpp_shr1(float src, float oldv) {
    return __int_as_float(__builtin_amdgcn_update_dpp(
        __float_as_int(oldv), __float_as_int(src), 0x138, 0xF, 0xF, false));
}
__device__ __forceinline__ float dpp_shl1(float src, float oldv) {
    return __int_as_float(__builtin_amdgcn_update_dpp(
        __float_as_int(oldv), __float_as_int(src), 0x130, 0xF, 0xF, false));
}
__device__ __forceinline__ float dpp_shr1z(float src) {
    return __int_as_float(__builtin_amdgcn_update_dpp(
        0, __float_as_int(src), 0x138, 0xF, 0xF, true));
}
__device__ __forceinline__ float dpp_shl1z(float src) {
    return __int_as_float(__builtin_amdgcn_update_dpp(
        0, __float_as_int(src), 0x130, 0xF, 0xF, true));
}

// ---------------- Kernel 1: all-register rolling canny front-end (DPP) --------------
// One wave per (image, 32-row band). Lane owns 4 contiguous cols [4l,4l+3].
// Mask-bit convention: word j of a row = cols {4l+j}, bit l = col 4l+j
// (k_hyst/k_diff below use the matching dilation).
__global__ __launch_bounds__(256, 3) void k_edges(
    const float* __restrict__ pred, const float* __restrict__ batch,
    u64* __restrict__ masks, double* __restrict__ sse)
{
    const int wv = threadIdx.x >> 6, lane = threadIdx.x & 63;
    const int band = blockIdx.x * 4 + wv;            // 0..7
    const int iy   = blockIdx.y;                     // 0..383
    const int R0 = band * 32, R1 = R0 + 31;
    const bool isPred = iy < NIMG;
    const float* img  = isPred ? pred  + (size_t)iy * NPIX : batch + (size_t)(iy - NIMG) * NPIX;
    const float* oimg = isPred ? batch + (size_t)iy * NPIX : pred  + (size_t)(iy - NIMG) * NPIX;
    u64* mout = masks + (size_t)iy * 2048;
    const int mlo = isPred ? R0 : R0 + 16;           // MSE row split between the two waves
    const int mhi = isPred ? R0 + 15 : R1;

    const float W0 = 0.0544886850f, W1 = 0.2442013420f, W2 = 0.4026199469f;
    const float LO2 = 0.1f * 0.1f, HI2 = 0.2f * 0.2f;
    const float T1 = 0.41421356237f, T2 = 2.41421356237f;

    float hw0[4], hw1[4], hw2[4], hw3[4], hw4[4];    // h-blur rows b-2..b+2
    float bo0[4], bo1[4], bo2[4];                    // v-blur rows b-2,b-1,b
    float mgA[4], mgB[4], mgC[4];                    // mag2 ring rows r-1,r,r+1
    float mgAL, mgAR, mgBL, mgBR, mgCL, mgCR;
    float gxp[4], gyp[4];                            // sobel of row r (prev iter)
    float4 cur, ocur = make_float4(0.f, 0.f, 0.f, 0.f);
    float acc = 0.f;
    const float4* pi = nullptr;                      // interior raw-row stream
    u64* mo = nullptr;                               // interior mask-row stream

    #pragma unroll
    for (int k = 0; k < 4; ++k) {
        hw0[k]=hw1[k]=hw2[k]=hw3[k]=hw4[k]=0.f; bo0[k]=bo1[k]=bo2[k]=0.f;
        mgA[k]=mgB[k]=mgC[k]=0.f; gxp[k]=gyp[k]=0.f;
    }
    mgAL=mgAR=mgBL=mgBR=mgCL=mgCR=0.f;

    const int bstart = R0 - 6;
    cur = *(const float4*)(img + refl(bstart + 2) * 256 + (lane << 2));

    auto step = [&](const int b, const bool FAST) {
        // ---- loads: raw row b+3; counterpart row b+3 (consumed next iter) ----
        float4 nxt;
        if (FAST) { nxt = *pi; pi += 64; }
        else      nxt = *(const float4*)(img + refl(b + 3) * 256 + (lane << 2));
        float4 onxt = ocur;
        if (b + 3 >= mlo && b + 3 <= mhi)
            onxt = *(const float4*)(oimg + ((b + 3) << 8) + (lane << 2));

        // ---- h-blur row b+2 (DPP cross-lane, reflect seams folded into old) ----
        float Lz = dpp_shr1(cur.z, cur.z);   // col 4l-2 ; lane0: refl(-2)=2 -> cur.z
        float Lw = dpp_shr1(cur.w, cur.y);   // col 4l-1 ; lane0: refl(-1)=1 -> cur.y
        float Rx = dpp_shl1(cur.x, cur.z);   // col 4l+4 ; lane63: refl(256)=254 -> cur.z
        float Ry = dpp_shl1(cur.y, cur.y);   // col 4l+5 ; lane63: refl(257)=253 -> cur.y
        float hb[4];
        hb[0] = W0*(Lz + cur.z)  + W1*(Lw + cur.y)    + W2*cur.x;
        hb[1] = W0*(Lw + cur.w)  + W1*(cur.x + cur.z) + W2*cur.y;
        hb[2] = W0*(cur.x + Rx)  + W1*(cur.y + cur.w) + W2*cur.z;
        hb[3] = W0*(cur.y + Ry)  + W1*(cur.z + Rx)    + W2*cur.w;

        // ---- v-blur row b (register window) ----
        #pragma unroll
        for (int k = 0; k < 4; ++k) {
            hw0[k]=hw1[k]; hw1[k]=hw2[k]; hw2[k]=hw3[k]; hw3[k]=hw4[k]; hw4[k]=hb[k];
            float bl = W0*(hw0[k]+hw4[k]) + W1*(hw1[k]+hw3[k]) + W2*hw2[k];
            bo0[k]=bo1[k]; bo1[k]=bo2[k]; bo2[k]=bl;
        }

        // ---- t,u row m=b-1; gx,gy,mag2 ----
        const int m = b - 1;
        float t[4], u[4];
        #pragma unroll
        for (int k = 0; k < 4; ++k) {
            float lo = bo0[k], hi = bo2[k];
            if (!FAST) { if (m == 0) lo = bo1[k]; if (m == 255) hi = bo1[k]; }
            t[k] = lo + 2.f*bo1[k] + hi;
            u[k] = hi - lo;
        }
        float Lt = dpp_shr1(t[3], t[0]), Rt = dpp_shl1(t[0], t[3]);   // clamp seams
        float Lu = dpp_shr1(u[3], u[0]), Ru = dpp_shl1(u[0], u[3]);
        float gx[4], gy[4], mg[4];
        gx[0] = t[1] - Lt;  gx[1] = t[2] - t[0];  gx[2] = t[3] - t[1];  gx[3] = Rt - t[2];
        gy[0] = Lu  + 2.f*u[0] + u[1];
        gy[1] = u[0] + 2.f*u[1] + u[2];
        gy[2] = u[1] + 2.f*u[2] + u[3];
        gy[3] = u[2] + 2.f*u[3] + Ru;
        #pragma unroll
        for (int k = 0; k < 4; ++k) mg[k] = fmaf(gx[k], gx[k], fmaf(gy[k], gy[k], 1e-6f));
        if (!FAST && (m < 0 || m > 255)) {
            #pragma unroll
            for (int k = 0; k < 4; ++k) mg[k] = 0.f;
        }
        float Lm = dpp_shr1z(mg[3]), Rm = dpp_shl1z(mg[0]);           // zero-pad seams

        // ---- rotate mag ring: A=row b-3, B=row b-2, C=row b-1 ----
        #pragma unroll
        for (int k = 0; k < 4; ++k) { mgA[k]=mgB[k]; mgB[k]=mgC[k]; mgC[k]=mg[k]; }
        mgAL=mgBL; mgBL=mgCL; mgCL=Lm;  mgAR=mgBR; mgBR=mgCR; mgCR=Rm;

        // ---- NMS + threshold row r = b-2 ----
        const int r = b - 2;
        if (FAST || (r >= R0 && r <= R1)) {
            bool wk[4], st[4];
            #pragma unroll
            for (int k = 0; k < 4; ++k) {
                float gxv = gxp[k], gyv = gyp[k];
                float ax = fabsf(gxv), ay = fabsf(gyv);
                bool horiz = (ay <= T1 * ax);
                bool vert  = (ay >= T2 * ax);
                bool d45   = ((__float_as_uint(gxv) ^ __float_as_uint(gyv)) >> 31) == 0u;
                float Bp  = (k < 3) ? mgB[k+1] : mgBR;
                float Bmv = (k > 0) ? mgB[k-1] : mgBL;
                float Ap  = (k < 3) ? mgA[k+1] : mgAR;
                float Amv = (k > 0) ? mgA[k-1] : mgAL;
                float Cp  = (k < 3) ? mgC[k+1] : mgCR;
                float Cmv = (k > 0) ? mgC[k-1] : mgCL;
                float m1 = d45 ? Ap  : Cp;   m1 = vert ? mgC[k] : m1;  m1 = horiz ? Bp  : m1;
                float m2 = d45 ? Cmv : Amv;  m2 = vert ? mgA[k] : m2;  m2 = horiz ? Bmv : m2;
                float v = mgB[k];
                bool keep = (v > m1) && (v > m2);
                wk[k] = keep && (v > LO2) && !(v > HI2);
                st[k] = keep && (v > HI2);
            }
            u64 bw0 = __ballot(wk[0]), bw1 = __ballot(wk[1]), bw2 = __ballot(wk[2]), bw3 = __ballot(wk[3]);
            u64 bs0 = __ballot(st[0]), bs1 = __ballot(st[1]), bs2 = __ballot(st[2]), bs3 = __ballot(st[3]);
            if (lane == 0) {
                u64* mrow = FAST ? mo : (mout + r * 4);
                ulonglong2 v2;
                v2.x = bw0; v2.y = bw1; ((ulonglong2*)mrow)[0] = v2;
                v2.x = bw2; v2.y = bw3; ((ulonglong2*)mrow)[1] = v2;
                v2.x = bs0; v2.y = bs1; ((ulonglong2*)(mrow + 1024))[0] = v2;
                v2.x = bs2; v2.y = bs3; ((ulonglong2*)(mrow + 1024))[1] = v2;
            }
            if (FAST) mo += 4;
        }

        // ---- MSE row b+2 + rotate sobel regs ----
        if (b + 2 >= mlo && b + 2 <= mhi) {
            float dx = cur.x - ocur.x, dy = cur.y - ocur.y;
            float dz = cur.z - ocur.z, dw = cur.w - ocur.w;
            acc += dx*dx + dy*dy + dz*dz + dw*dw;
        }
        #pragma unroll
        for (int k = 0; k < 4; ++k) { gxp[k] = gx[k]; gyp[k] = gy[k]; }
        cur = nxt; ocur = onxt;
    };

    int b = bstart;
    for (; b <= R0 + 1; ++b) step(b, false);             // prime (8 iters, NMS auto-off)
    const int bfe = (R1 + 2 < 252) ? (R1 + 2) : 252;
    pi = (const float4*)(img + (size_t)(b + 3) * 256) + lane;
    mo = mout + (size_t)(b - 2) * 4;
    #pragma unroll 15
    for (; b <= bfe; ++b) step(b, true);                 // branch-free interior
    for (; b <= R1 + 2; ++b) step(b, false);             // bottom boundary (band 7)

    for (int off = 32; off; off >>= 1) acc += __shfl_down(acc, off);
    if (lane == 0)
        atomicAdd(&sse[(blockIdx.y * 2 + blockIdx.x) & 63], (double)acc);
}

// ---------------- Kernel 2: per-image hysteresis fixpoint (rows in registers) -------
// Bit convention: word j bit l = col 4l+j (dilation shifts accordingly).
__global__ __launch_bounds__(256) void k_hyst(u64* __restrict__ masks)
{
    const int im = blockIdx.x;                       // image 0..383
    u64* m = masks + (size_t)im * 2048;
    const int r = threadIdx.x;                       // row 0..255
    __shared__ u64 hd[4][256];
    __shared__ int flg[2];
    ulonglong2 wa = *(const ulonglong2*)(m + r*4);
    ulonglong2 wb = *(const ulonglong2*)(m + r*4 + 2);
    ulonglong2 sa = *(const ulonglong2*)(m + 1024 + r*4);
    ulonglong2 sb = *(const ulonglong2*)(m + 1024 + r*4 + 2);
    u64 ww0=wa.x, ww1=wa.y, ww2=wb.x, ww3=wb.y;
    u64 s0=sa.x, s1=sa.y, s2=sb.x, s3=sb.y;
    if (r < 2) flg[r] = 0;
    const int up = (r > 0) ? r - 1 : 0, dn = (r < 255) ? r + 1 : 255;
    for (int k = 0;; ++k) {
        u64 h0 = s0 | (s3 << 1) | s1;               // col-1 of word0 = word3<<1
        u64 h1 = s1 | s0 | s2;
        u64 h2 = s2 | s1 | s3;
        u64 h3 = s3 | s2 | (s0 >> 1);               // col+1 of word3 = word0>>1
        hd[0][r]=h0; hd[1][r]=h1; hd[2][r]=h2; hd[3][r]=h3;
        if (r == 0) flg[(k+1)&1] = 0;
        __syncthreads();
        u64 n0 = s0 | ((h0 | hd[0][up] | hd[0][dn]) & ww0);
        u64 n1 = s1 | ((h1 | hd[1][up] | hd[1][dn]) & ww1);
        u64 n2 = s2 | ((h2 | hd[2][up] | hd[2][dn]) & ww2);
        u64 n3 = s3 | ((h3 | hd[3][up] | hd[3][dn]) & ww3);
        bool ch = ((n0^s0) | (n1^s1) | (n2^s2) | (n3^s3)) != 0ULL;
        s0=n0; s1=n1; s2=n2; s3=n3;
        if (ch) flg[k&1] = 1;
        __syncthreads();
        if (!flg[k&1]) break;
    }
    ulonglong2 o;
    o.x = s0; o.y = s1; *(ulonglong2*)(m + 1024 + r*4)     = o;
    o.x = s2; o.y = s3; *(ulonglong2*)(m + 1024 + r*4 + 2) = o;
}

// ---------------- Kernel 3: XOR-popcount of final strong masks ----------------------
__global__ __launch_bounds__(256) void k_diff(const u64* __restrict__ masks, u64* __restrict__ cnt)
{
    const int b = blockIdx.x;                        // pair 0..191
    const u64* sp = masks + (size_t)b * 2048 + 1024;
    const u64* st = masks + (size_t)(b + NIMG) * 2048 + 1024;
    int c = 0;
    for (int k = threadIdx.x; k < 1024; k += 256)
        c += __popcll(sp[k] ^ st[k]);
    for (int off = 32; off; off >>= 1) c += __shfl_down(c, off);
    __shared__ int wsum[4];
    if ((threadIdx.x & 63) == 0) wsum[threadIdx.x >> 6] = c;
    __syncthreads();
    if (threadIdx.x == 0)
        atomicAdd(cnt, (u64)(wsum[0] + wsum[1] + wsum[2] + wsum[3]));
}

// ---------------- Kernel 4: combine --------------------------------------------------
__global__ void k_final(const double* __restrict__ sse, const u64* __restrict__ cnt,
                        float* __restrict__ out)
{
    double s = 0.0;
    for (int i = 0; i < 64; ++i) s += sse[i];
    float mse1 = (float)(s / (double)N_TOTAL);
    float mse2 = (float)((double)(*cnt) / (double)N_TOTAL);
    out[0] = 0.85f * mse1 + (1.0f - 0.85f) * mse2;
}

extern "C" void kernel_launch(void* const* d_in, const int* in_sizes, int n_in,
                              void* d_out, int out_size, void* d_ws, size_t ws_size,
                              hipStream_t stream)
{
    const float* pred  = (const float*)d_in[0];
    const float* batch = (const float*)d_in[1];
    float* out = (float*)d_out;
    double* sse = (double*)d_ws;                       // 64 doubles
    u64* cnt    = (u64*)((char*)d_ws + 512);
    u64* masks  = (u64*)((char*)d_ws + 1024);          // 384 * 2048 u64

    hipMemsetAsync(d_ws, 0, 1024, stream);
    dim3 g1(2, 384);
    k_edges<<<g1, 256, 0, stream>>>(pred, batch, masks, sse);
    k_hyst<<<384, 256, 0, stream>>>(masks);
    k_diff<<<192, 256, 0, stream>>>(masks, cnt);
    k_final<<<1, 1, 0, stream>>>(sse, cnt, out);
}

// Round 7
// 69.475 us; speedup vs baseline: 3.3643x; 1.0988x over previous
//
#include <hip/hip_runtime.h>

#define NIMG 192
#define NPIX (256*256)
#define N_TOTAL (192*65536)
typedef unsigned long long u64;

__device__ __forceinline__ int refl(int i){ i = i < 0 ? -i : i; return i > 255 ? 510 - i : i; }

// DPP wave-wide lane shifts. shr1: lane n <- n-1 (lane0 -> oldv). shl1: lane n <- n+1
// (lane63 -> oldv). *z: invalid lane -> 0.
__device__ __forceinline__ float dpp_shr1(float src, float oldv) {
    return __int_as_float(__builtin_amdgcn_update_dpp(
        __float_as_int(oldv), __float_as_int(src), 0x138, 0xF, 0xF, false));
}
__device__ __forceinline__ float dpp_shl1(float src, float oldv) {
    return __int_as_float(__builtin_amdgcn_update_dpp(
        __float_as_int(oldv), __float_as_int(src), 0x130, 0xF, 0xF, false));
}
__device__ __forceinline__ float dpp_shr1z(float src) {
    return __int_as_float(__builtin_amdgcn_update_dpp(
        0, __float_as_int(src), 0x138, 0xF, 0xF, true));
}
__device__ __forceinline__ float dpp_shl1z(float src) {
    return __int_as_float(__builtin_amdgcn_update_dpp(
        0, __float_as_int(src), 0x130, 0xF, 0xF, true));
}

// ---------------- Kernel 1: all-register rolling canny front-end ----------------
// One wave per (image, 32-row band). Lane owns 4 contiguous cols [4l,4l+3].
// Mask word j of a row = cols {4l+j}, bit l = col 4l+j.
// Weak words deliberately include strong bits (hysteresis-invariant) so that
// weak = ballot(v > max3(m1,m2,LO2)), strong = ballot(v > max3(m1,m2,HI2)).
__global__ __launch_bounds__(256, 3) void k_edges(
    const float* __restrict__ pred, const float* __restrict__ batch,
    u64* __restrict__ masks, double* __restrict__ sse)
{
    const int wv = threadIdx.x >> 6, lane = threadIdx.x & 63;
    const int band = blockIdx.x * 4 + wv;            // 0..7
    const int iy   = blockIdx.y;                     // 0..383
    const int R0 = band * 32, R1 = R0 + 31;
    const bool isPred = iy < NIMG;
    const float* img  = isPred ? pred  + (size_t)iy * NPIX : batch + (size_t)(iy - NIMG) * NPIX;
    const float* oimg = isPred ? batch + (size_t)iy * NPIX : pred  + (size_t)(iy - NIMG) * NPIX;
    u64* mout = masks + (size_t)iy * 2048;
    const int mlo = isPred ? R0 : R0 + 16;           // 16-row MSE window per wave

    const float W0 = 0.0544886850f, W1 = 0.2442013420f, W2 = 0.4026199469f;
    const float LO2 = 0.01f, HI2 = 0.04f, T1 = 0.41421356237f;

    // State entering a row-step b:
    //  hwB..hwE = h-blur rows b-2..b+1 ; boP,boQ = v-blur rows b-2,b-1
    //  mgA (+AL,AR) = mag2 row b-3 ; mgB (+BL,BR) = mag2 row b-2
    //  gxp,gyp = sobel row b-2 ; cur = raw row b+2
    float hwB[4], hwC[4], hwD[4], hwE[4], boP[4], boQ[4];
    float mgA[4], mgB[4], mgAL, mgAR, mgBL, mgBR, gxp[4], gyp[4];
    float4 cur;
    float acc = 0.f;
    const float4 *pi = nullptr, *po = nullptr;
    u64* mo = nullptr;

    #pragma unroll
    for (int k = 0; k < 4; ++k) {
        hwB[k]=hwC[k]=hwD[k]=hwE[k]=0.f; boP[k]=boQ[k]=0.f;
        mgA[k]=mgB[k]=0.f; gxp[k]=gyp[k]=0.f;
    }
    mgAL=mgAR=mgBL=mgBR=0.f;

    auto donms = [&](const float mgC[4], const float CL, const float CR, u64* dst) {
        u64 wB[4], sB[4];
        #pragma unroll
        for (int k = 0; k < 4; ++k) {
            const float gxv = gxp[k], gyv = gyp[k];
            const float ax = fabsf(gxv), ay = fabsf(gyv);
            const bool horiz = (ay <= T1 * ax);
            const bool vert  = (ax <= T1 * ay);          // == ay >= ax/T1 = ax*T2
            const bool d45 = (int)(__float_as_uint(gxv) ^ __float_as_uint(gyv)) >= 0;
            const float Ap = (k < 3) ? mgA[k+1] : mgAR, Am = (k > 0) ? mgA[k-1] : mgAL;
            const float Bp = (k < 3) ? mgB[k+1] : mgBR, Bm = (k > 0) ? mgB[k-1] : mgBL;
            const float Cp = (k < 3) ? mgC[k+1] : CR,   Cm = (k > 0) ? mgC[k-1] : CL;
            const float m1 = horiz ? Bp : (vert ? mgC[k] : (d45 ? Ap : Cp));
            const float m2 = horiz ? Bm : (vert ? mgA[k] : (d45 ? Cm : Am));
            const float M  = fmaxf(fmaxf(m1, m2), LO2);  // v_max3
            const float v  = mgB[k];
            wB[k] = __ballot(v > M);                     // weak OR strong
            sB[k] = __ballot(v > fmaxf(M, HI2));         // strong
        }
        if (lane == 0) {
            ulonglong2 q;
            q.x = wB[0]; q.y = wB[1]; ((ulonglong2*)dst)[0] = q;
            q.x = wB[2]; q.y = wB[3]; ((ulonglong2*)dst)[1] = q;
            q.x = sB[0]; q.y = sB[1]; ((ulonglong2*)(dst + 1024))[0] = q;
            q.x = sB[2]; q.y = sB[3]; ((ulonglong2*)(dst + 1024))[1] = q;
        }
    };

    // generic (boundary) row step
    auto steprow = [&](const int b) {
        float4 nxt = *(const float4*)(img + (size_t)refl(b + 3) * 256 + (lane << 2));
        const int m = b - 1, r = b - 2;
        const bool doM = (b + 2 >= mlo) && (b + 2 <= mlo + 15);
        float4 oc;
        if (doM) oc = *(const float4*)(oimg + (size_t)(b + 2) * 256 + (lane << 2));
        float Lz = dpp_shr1(cur.z, cur.z), Lw = dpp_shr1(cur.w, cur.y);
        float Rx = dpp_shl1(cur.x, cur.z), Ry = dpp_shl1(cur.y, cur.y);
        float hb[4];
        hb[0] = W0*(Lz + cur.z) + W1*(Lw + cur.y)    + W2*cur.x;
        hb[1] = W0*(Lw + cur.w) + W1*(cur.x + cur.z) + W2*cur.y;
        hb[2] = W0*(cur.x + Rx) + W1*(cur.y + cur.w) + W2*cur.z;
        hb[3] = W0*(cur.y + Ry) + W1*(cur.z + Rx)    + W2*cur.w;
        float t[4], u[4], blv[4];
        #pragma unroll
        for (int k = 0; k < 4; ++k) {
            blv[k] = W0*(hwB[k] + hb[k]) + W1*(hwC[k] + hwE[k]) + W2*hwD[k];
            float lo = (m == 0)   ? boQ[k] : boP[k];
            float hi = (m == 255) ? boQ[k] : blv[k];
            t[k] = lo + 2.f*boQ[k] + hi;
            u[k] = hi - lo;
        }
        float Lt = dpp_shr1(t[3], t[0]), Rt = dpp_shl1(t[0], t[3]);
        float Lu = dpp_shr1(u[3], u[0]), Ru = dpp_shl1(u[0], u[3]);
        float gx[4], gy[4], mgC[4];
        gx[0] = t[1] - Lt; gx[1] = t[2] - t[0]; gx[2] = t[3] - t[1]; gx[3] = Rt - t[2];
        gy[0] = (Lu + u[1]) + 2.f*u[0];  gy[1] = (u[0] + u[2]) + 2.f*u[1];
        gy[2] = (u[1] + u[3]) + 2.f*u[2]; gy[3] = (u[2] + Ru) + 2.f*u[3];
        #pragma unroll
        for (int k = 0; k < 4; ++k) mgC[k] = fmaf(gx[k], gx[k], fmaf(gy[k], gy[k], 1e-6f));
        if (m < 0 || m > 255) { mgC[0]=mgC[1]=mgC[2]=mgC[3]=0.f; }
        float CL = dpp_shr1z(mgC[3]), CR = dpp_shl1z(mgC[0]);
        if (r >= R0 && r <= R1) donms(mgC, CL, CR, mout + r * 4);
        if (doM) {
            float dx = cur.x - oc.x, dy = cur.y - oc.y, dz = cur.z - oc.z, dw = cur.w - oc.w;
            acc += dx*dx + dy*dy + dz*dz + dw*dw;
        }
        #pragma unroll
        for (int k = 0; k < 4; ++k) {
            hwB[k]=hwC[k]; hwC[k]=hwD[k]; hwD[k]=hwE[k]; hwE[k]=hb[k];
            boP[k]=boQ[k]; boQ[k]=blv[k];
            mgA[k]=mgB[k]; mgB[k]=mgC[k];
            gxp[k]=gx[k];  gyp[k]=gy[k];
        }
        mgAL=mgBL; mgBL=CL; mgAR=mgBR; mgBR=CR;
        cur = nxt;
    };

    // branch-free interior row step (no refl/clamp/row-guards, incremental ptrs)
    auto fastrow = [&](const int b) {
        float4 nxt = *pi; pi += 64;
        const bool doM = ((unsigned)(b + 2 - mlo) <= 15u);
        float4 oc;
        if (doM) oc = *po;
        po += 64;
        float Lz = dpp_shr1(cur.z, cur.z), Lw = dpp_shr1(cur.w, cur.y);
        float Rx = dpp_shl1(cur.x, cur.z), Ry = dpp_shl1(cur.y, cur.y);
        float hb[4];
        hb[0] = W0*(Lz + cur.z) + W1*(Lw + cur.y)    + W2*cur.x;
        hb[1] = W0*(Lw + cur.w) + W1*(cur.x + cur.z) + W2*cur.y;
        hb[2] = W0*(cur.x + Rx) + W1*(cur.y + cur.w) + W2*cur.z;
        hb[3] = W0*(cur.y + Ry) + W1*(cur.z + Rx)    + W2*cur.w;
        float t[4], u[4], blv[4];
        #pragma unroll
        for (int k = 0; k < 4; ++k) {
            blv[k] = W0*(hwB[k] + hb[k]) + W1*(hwC[k] + hwE[k]) + W2*hwD[k];
            t[k] = boP[k] + 2.f*boQ[k] + blv[k];
            u[k] = blv[k] - boP[k];
        }
        float Lt = dpp_shr1(t[3], t[0]), Rt = dpp_shl1(t[0], t[3]);
        float Lu = dpp_shr1(u[3], u[0]), Ru = dpp_shl1(u[0], u[3]);
        float gx[4], gy[4], mgC[4];
        gx[0] = t[1] - Lt; gx[1] = t[2] - t[0]; gx[2] = t[3] - t[1]; gx[3] = Rt - t[2];
        gy[0] = (Lu + u[1]) + 2.f*u[0];  gy[1] = (u[0] + u[2]) + 2.f*u[1];
        gy[2] = (u[1] + u[3]) + 2.f*u[2]; gy[3] = (u[2] + Ru) + 2.f*u[3];
        #pragma unroll
        for (int k = 0; k < 4; ++k) mgC[k] = fmaf(gx[k], gx[k], fmaf(gy[k], gy[k], 1e-6f));
        float CL = dpp_shr1z(mgC[3]), CR = dpp_shl1z(mgC[0]);
        donms(mgC, CL, CR, mo); mo += 4;
        if (doM) {
            float dx = cur.x - oc.x, dy = cur.y - oc.y, dz = cur.z - oc.z, dw = cur.w - oc.w;
            acc += dx*dx + dy*dy + dz*dz + dw*dw;
        }
        #pragma unroll
        for (int k = 0; k < 4; ++k) {
            hwB[k]=hwC[k]; hwC[k]=hwD[k]; hwD[k]=hwE[k]; hwE[k]=hb[k];
            boP[k]=boQ[k]; boQ[k]=blv[k];
            mgA[k]=mgB[k]; mgB[k]=mgC[k];
            gxp[k]=gx[k];  gyp[k]=gy[k];
        }
        mgAL=mgBL; mgBL=CL; mgAR=mgBR; mgBR=CR;
        cur = nxt;
    };

    int b = R0 - 6;
    cur = *(const float4*)(img + (size_t)refl(b + 2) * 256 + (lane << 2));
    for (; b <= R0 + 3; ++b) steprow(b);                 // prime + rows R0,R0+1 (10 steps)
    pi = (const float4*)img  + ((R0 + 7) << 6) + lane;   // raw row b+3 (b=R0+4)
    po = (const float4*)oimg + ((R0 + 6) << 6) + lane;   // counterpart row b+2
    mo = mout + (size_t)(R0 + 2) * 4;
    const int nt = (band == 7) ? 8 : 10;                 // triples: 24 or 30 interior rows
    for (int tt = 0; tt < nt; ++tt) {
        fastrow(b); fastrow(b + 1); fastrow(b + 2); b += 3;
    }
    for (; b <= R1 + 2; ++b) steprow(b);                 // band-7 epilogue (rows 250..255)

    for (int off = 32; off; off >>= 1) acc += __shfl_down(acc, off);
    if (lane == 0)
        atomicAdd(&sse[(blockIdx.y * 2 + blockIdx.x) & 63], (double)acc);
}

// ------- Kernel 2: per-pair hysteresis fixpoint + inline strong-diff count ----------
// Bit convention: word j bit l = col 4l+j.
__global__ __launch_bounds__(256) void k_hyst(const u64* __restrict__ masks,
                                              u64* __restrict__ cnt)
{
    const int pr = blockIdx.x;                       // pair 0..191
    const u64* mp = masks + (size_t)pr * 2048;
    const u64* mt = masks + (size_t)(pr + NIMG) * 2048;
    const int r = threadIdx.x;                       // row 0..255
    __shared__ u64 hd[8][256];
    __shared__ int flg[2];
    __shared__ int wsum[4];
    ulonglong2 a0 = ((const ulonglong2*)(mp + r*4))[0];
    ulonglong2 a1 = ((const ulonglong2*)(mp + r*4))[1];
    ulonglong2 a2 = ((const ulonglong2*)(mp + 1024 + r*4))[0];
    ulonglong2 a3 = ((const ulonglong2*)(mp + 1024 + r*4))[1];
    ulonglong2 b0 = ((const ulonglong2*)(mt + r*4))[0];
    ulonglong2 b1 = ((const ulonglong2*)(mt + r*4))[1];
    ulonglong2 b2 = ((const ulonglong2*)(mt + 1024 + r*4))[0];
    ulonglong2 b3 = ((const ulonglong2*)(mt + 1024 + r*4))[1];
    u64 pw0=a0.x, pw1=a0.y, pw2=a1.x, pw3=a1.y;
    u64 ps0=a2.x, ps1=a2.y, ps2=a3.x, ps3=a3.y;
    u64 tw0=b0.x, tw1=b0.y, tw2=b1.x, tw3=b1.y;
    u64 ts0=b2.x, ts1=b2.y, ts2=b3.x, ts3=b3.y;
    if (r < 2) flg[r] = 0;
    const int up = r ? r - 1 : 0, dn = (r < 255) ? r + 1 : 255;
    for (int k = 0;; ++k) {
        u64 hp0 = ps0 | (ps3 << 1) | ps1;
        u64 hp1 = ps1 | ps0 | ps2;
        u64 hp2 = ps2 | ps1 | ps3;
        u64 hp3 = ps3 | ps2 | (ps0 >> 1);
        u64 ht0 = ts0 | (ts3 << 1) | ts1;
        u64 ht1 = ts1 | ts0 | ts2;
        u64 ht2 = ts2 | ts1 | ts3;
        u64 ht3 = ts3 | ts2 | (ts0 >> 1);
        hd[0][r]=hp0; hd[1][r]=hp1; hd[2][r]=hp2; hd[3][r]=hp3;
        hd[4][r]=ht0; hd[5][r]=ht1; hd[6][r]=ht2; hd[7][r]=ht3;
        if (r == 0) flg[(k + 1) & 1] = 0;
        __syncthreads();
        u64 n0 = ps0 | ((hp0 | hd[0][up] | hd[0][dn]) & pw0);
        u64 n1 = ps1 | ((hp1 | hd[1][up] | hd[1][dn]) & pw1);
        u64 n2 = ps2 | ((hp2 | hd[2][up] | hd[2][dn]) & pw2);
        u64 n3 = ps3 | ((hp3 | hd[3][up] | hd[3][dn]) & pw3);
        u64 m0 = ts0 | ((ht0 | hd[4][up] | hd[4][dn]) & tw0);
        u64 m1 = ts1 | ((ht1 | hd[5][up] | hd[5][dn]) & tw1);
        u64 m2 = ts2 | ((ht2 | hd[6][up] | hd[6][dn]) & tw2);
        u64 m3 = ts3 | ((ht3 | hd[7][up] | hd[7][dn]) & tw3);
        u64 chg = (n0^ps0)|(n1^ps1)|(n2^ps2)|(n3^ps3)|(m0^ts0)|(m1^ts1)|(m2^ts2)|(m3^ts3);
        ps0=n0; ps1=n1; ps2=n2; ps3=n3; ts0=m0; ts1=m1; ts2=m2; ts3=m3;
        if (chg) flg[k & 1] = 1;
        __syncthreads();
        if (!flg[k & 1]) break;
    }
    int c = __popcll(ps0^ts0) + __popcll(ps1^ts1) + __popcll(ps2^ts2) + __popcll(ps3^ts3);
    for (int off = 32; off; off >>= 1) c += __shfl_down(c, off);
    if ((threadIdx.x & 63) == 0) wsum[threadIdx.x >> 6] = c;
    __syncthreads();
    if (threadIdx.x == 0)
        atomicAdd(cnt, (u64)(wsum[0] + wsum[1] + wsum[2] + wsum[3]));
}

// ---------------- Kernel 3: combine --------------------------------------------------
__global__ void k_final(const double* __restrict__ sse, const u64* __restrict__ cnt,
                        float* __restrict__ out)
{
    double s = 0.0;
    for (int i = 0; i < 64; ++i) s += sse[i];
    float mse1 = (float)(s / (double)N_TOTAL);
    float mse2 = (float)((double)(*cnt) / (double)N_TOTAL);
    out[0] = 0.85f * mse1 + (1.0f - 0.85f) * mse2;
}

extern "C" void kernel_launch(void* const* d_in, const int* in_sizes, int n_in,
                              void* d_out, int out_size, void* d_ws, size_t ws_size,
                              hipStream_t stream)
{
    const float* pred  = (const float*)d_in[0];
    const float* batch = (const float*)d_in[1];
    float* out = (float*)d_out;
    double* sse = (double*)d_ws;                       // 64 doubles
    u64* cnt    = (u64*)((char*)d_ws + 512);
    u64* masks  = (u64*)((char*)d_ws + 1024);          // 384 * 2048 u64

    hipMemsetAsync(d_ws, 0, 1024, stream);
    dim3 g1(2, 384);
    k_edges<<<g1, 256, 0, stream>>>(pred, batch, masks, sse);
    k_hyst<<<192, 256, 0, stream>>>(masks, cnt);
    k_final<<<1, 1, 0, stream>>>(sse, cnt, out);
}